// Round 7
// baseline (925.702 us; speedup 1.0000x reference)
//
#include <hip/hip_runtime.h>

#define NN 100000     // nodes
#define NE 1600000    // edges
#define NGR 512       // graphs
#define KF 128        // IN_F == H1
#define H2F 256
#define NGRP 16
#define NFAM 10

#define CH 128                          // nodes per chunk
#define NCHUNK ((NN + CH - 1) / CH)     // 782
#define PT 6656                         // edges per partition tile
#define NT ((NE + PT - 1) / PT)         // 241
#define CSLACK 1024                     // per-chunk padded slack (>= 128*7 + 8)

typedef __attribute__((ext_vector_type(8))) short short8;
typedef __attribute__((ext_vector_type(4))) float floatx4;

__device__ __forceinline__ unsigned short f2bf(float f) {
  unsigned u = __float_as_uint(f);
  unsigned r = (u + 0x7fff + ((u >> 16) & 1)) >> 16;
  return (unsigned short)r;
}
__device__ __forceinline__ float2 bf2f(unsigned u) {
  float2 r;
  r.x = __uint_as_float(u << 16);
  r.y = __uint_as_float(u & 0xffff0000u);
  return r;
}

// ---------------- edge partition by dst chunk (dst>>7), LDS-staged ----------------

__global__ __launch_bounds__(256) void k_phist(const int* __restrict__ ei,
                                               int* __restrict__ mat) {
  __shared__ int lh[NCHUNK];
  int t0 = blockIdx.x, tid = threadIdx.x;
  for (int g = tid; g < NCHUNK; g += 256) lh[g] = 0;
  __syncthreads();
  int base = t0 * PT;
  int nv = min(PT, NE - base);
  for (int i = tid; i < nv; i += 256) atomicAdd(&lh[ei[NE + base + i] >> 7], 1);
  __syncthreads();
  for (int g = tid; g < NCHUNK; g += 256) mat[t0 * NCHUNK + g] = lh[g];
}

// column sums of mat -> tot[NCHUNK]; one wave per column
__global__ __launch_bounds__(256) void k_colsum(const int* __restrict__ mat,
                                                int* __restrict__ tot) {
  int g = blockIdx.x * 4 + (threadIdx.x >> 6);
  if (g >= NCHUNK) return;
  int lane = threadIdx.x & 63;
  int s = 0;
  for (int t = lane; t < NT; t += 64) s += mat[t * NCHUNK + g];
#pragma unroll
  for (int off = 32; off > 0; off >>= 1) s += __shfl_down(s, off);
  if (lane == 0) tot[g] = s;
}

// exclusive scan of tot[NCHUNK] -> cbase
__global__ __launch_bounds__(256) void k_scantot(const int* __restrict__ tot,
                                                 int* __restrict__ cbase) {
  __shared__ int ssc[256];
  int tid = threadIdx.x;
  int v4[4]; int loc = 0;
#pragma unroll
  for (int j = 0; j < 4; ++j) {
    int idx = tid * 4 + j;
    v4[j] = (idx < NCHUNK) ? tot[idx] : 0;
    loc += v4[j];
  }
  ssc[tid] = loc;
  __syncthreads();
  for (int off = 1; off < 256; off <<= 1) {
    int val = (tid >= off) ? ssc[tid - off] : 0;
    __syncthreads();
    ssc[tid] += val;
    __syncthreads();
  }
  int excl = ssc[tid] - loc;
#pragma unroll
  for (int j = 0; j < 4; ++j) {
    int idx = tid * 4 + j;
    if (idx < NCHUNK) cbase[idx] = excl;
    excl += v4[j];
  }
  if (tid == 255) cbase[NCHUNK] = excl;  // == NE
}

// per-column prefix over tiles; one wave/column
__global__ __launch_bounds__(256) void k_colfix(int* __restrict__ mat,
                                                const int* __restrict__ cbase) {
  int g = blockIdx.x * 4 + (threadIdx.x >> 6);
  if (g >= NCHUNK) return;
  int lane = threadIdx.x & 63;
  int v[4]; int loc = 0;
#pragma unroll
  for (int j = 0; j < 4; ++j) {
    int t = lane * 4 + j;
    v[j] = (t < NT) ? mat[t * NCHUNK + g] : 0;
    loc += v[j];
  }
  int incl = loc;
#pragma unroll
  for (int off = 1; off < 64; off <<= 1) {
    int o = __shfl_up(incl, off);
    if (lane >= off) incl += o;
  }
  int excl = incl - loc + cbase[g];
#pragma unroll
  for (int j = 0; j < 4; ++j) {
    int t = lane * 4 + j;
    if (t < NT) mat[t * NCHUNK + g] = excl;
    excl += v[j];
  }
}

__global__ __launch_bounds__(256) void k_pscatter(const int* __restrict__ ei,
                                                  const int* __restrict__ mat,
                                                  int2* __restrict__ erec) {
  __shared__ int2 stage[PT];
  __shared__ int lstart[NCHUNK];
  __shared__ int lrun[NCHUNK];
  __shared__ int loff[NCHUNK];
  __shared__ int ssc[256];
  int t0 = blockIdx.x, tid = threadIdx.x;
  for (int g = tid; g < NCHUNK; g += 256) lrun[g] = 0;
  __syncthreads();
  int base = t0 * PT;
  int nv = min(PT, NE - base);
  for (int i = tid; i < nv; i += 256) atomicAdd(&lrun[ei[NE + base + i] >> 7], 1);
  __syncthreads();
  int v4[4]; int loc = 0;
#pragma unroll
  for (int j = 0; j < 4; ++j) {
    int idx = tid * 4 + j;
    v4[j] = (idx < NCHUNK) ? lrun[idx] : 0;
    loc += v4[j];
  }
  ssc[tid] = loc;
  __syncthreads();
  for (int off = 1; off < 256; off <<= 1) {
    int val = (tid >= off) ? ssc[tid - off] : 0;
    __syncthreads();
    ssc[tid] += val;
    __syncthreads();
  }
  int excl = ssc[tid] - loc;
#pragma unroll
  for (int j = 0; j < 4; ++j) {
    int idx = tid * 4 + j;
    if (idx < NCHUNK) lstart[idx] = excl;
    excl += v4[j];
  }
  __syncthreads();
  for (int g = tid; g < NCHUNK; g += 256) {
    lrun[g] = lstart[g];
    loff[g] = mat[t0 * NCHUNK + g];
  }
  __syncthreads();
  for (int i = tid; i < nv; i += 256) {
    int s = ei[base + i], d = ei[NE + base + i];
    int pos = atomicAdd(&lrun[d >> 7], 1);
    stage[pos] = make_int2(s, d);
  }
  __syncthreads();
  for (int j = tid; j < nv; j += 256) {
    int2 r = stage[j];
    int g = r.y >> 7;
    erec[loff[g] + (j - lstart[g])] = r;
  }
}

// ---------------- per-chunk counting sort into padded per-node runs ----------------
// Each node's run is padded to x8 with dummy src NN (zero row). Runs are
// contiguous within the chunk's padded region [pb, pe); r1 = rowptr[n+1].

__global__ __launch_bounds__(256) void k_sort(const int2* __restrict__ erec,
                                              const int* __restrict__ cbase,
                                              int* __restrict__ esrc,
                                              int* __restrict__ rowptr,
                                              float* __restrict__ dinv) {
  __shared__ int hist[CH];
  __shared__ int lrun[CH];
  __shared__ int sc[256];
  const int c = blockIdx.x, tid = threadIdx.x;
  const int e0 = cbase[c], e1 = cbase[c + 1];
  const int nv = e1 - e0;
  const int pb = ((e0 + 7) & ~7) + c * CSLACK;
  const int pe = ((e1 + 7) & ~7) + (c + 1) * CSLACK;
  if (tid < CH) hist[tid] = 0;
  __syncthreads();
  for (int i = tid; i < nv; i += 256) atomicAdd(&hist[erec[e0 + i].y & (CH - 1)], 1);
  __syncthreads();
  int deg = (tid < CH) ? hist[tid] : 0;
  int pd = (deg + 7) & ~7;
  sc[tid] = pd;
  __syncthreads();
  for (int off = 1; off < 256; off <<= 1) {
    int val = (tid >= off) ? sc[tid - off] : 0;
    __syncthreads();
    sc[tid] += val;
    __syncthreads();
  }
  int excl = sc[tid] - pd;
  int node = c * CH + tid;
  if (tid < CH) {
    lrun[tid] = excl;
    if (node < NN) {
      rowptr[node] = pb + excl;
      dinv[node] = rsqrtf((float)(deg + 1));  // +1 self loop
    }
    if (node == NN) rowptr[NN] = pb + excl;
  }
  __syncthreads();
  for (int i = pb + tid; i < pe; i += 256) esrc[i] = NN;  // dummy fill
  __syncthreads();
  for (int i = tid; i < nv; i += 256) {
    int2 r = erec[e0 + i];
    int pos = atomicAdd(&lrun[r.y & (CH - 1)], 1);
    esrc[pb + pos] = r.x;
  }
}

// ---------------- zero the dummy rows (index NN) of xw1' and h1' ----------------

__global__ void k_zero(unsigned* __restrict__ a, unsigned* __restrict__ b) {
  int t = threadIdx.x;  // 64
  a[(size_t)NN * 64 + t] = 0;
  b[(size_t)NN * 64 + t] = 0;
}

// ---------------- W1 pre-swizzle into MFMA B-fragment layout ----------------

__global__ void k_prepB(const float* __restrict__ W, unsigned short* __restrict__ Bp,
                        int Ncol) {
  int idx = blockIdx.x * 256 + threadIdx.x;
  int total = 128 * Ncol;
  if (idx >= total) return;
  int NCH = Ncol >> 4;
  int j = idx & 7;
  int l = (idx >> 3) & 63;
  int rest = idx >> 9;
  int nc = rest % NCH;
  int kc = rest / NCH;
  int k = kc * 32 + (l >> 4) * 8 + j;
  int nn = nc * 16 + (l & 15);
  Bp[idx] = f2bf(W[k * Ncol + nn]);
}

// ---------------- MFMA GEMM1: xw1'[n] = dinv[n] * (x[n] @ W1), bf16 out ----------------

__global__ __launch_bounds__(256) void k_gemm_mfma(const float* __restrict__ A,
                                                   const unsigned short* __restrict__ Bp,
                                                   const float* __restrict__ dinv,
                                                   unsigned short* __restrict__ C) {
  constexpr int K = 128;
  constexpr int N = KF;
  constexpr int NCH = N / 16;
  const int wv = blockIdx.x * 4 + (threadIdx.x >> 6);
  const int row0 = wv * 16;
  if (row0 >= NN) return;  // 100000 % 16 == 0
  const int lane = threadIdx.x & 63;
  const int m = lane & 15;
  const int q = lane >> 4;

  floatx4 acc[NCH];
#pragma unroll
  for (int i = 0; i < NCH; ++i) acc[i] = (floatx4){0.f, 0.f, 0.f, 0.f};

  const int arow = row0 + m;
#pragma unroll
  for (int kc = 0; kc < 4; ++kc) {
    const float* ap = A + (size_t)arow * K + kc * 32 + q * 8;
    float4 f0 = *(const float4*)ap;
    float4 f1 = *(const float4*)(ap + 4);
    short8 af;
    af[0] = (short)f2bf(f0.x); af[1] = (short)f2bf(f0.y);
    af[2] = (short)f2bf(f0.z); af[3] = (short)f2bf(f0.w);
    af[4] = (short)f2bf(f1.x); af[5] = (short)f2bf(f1.y);
    af[6] = (short)f2bf(f1.z); af[7] = (short)f2bf(f1.w);
    const unsigned short* bp = Bp + (size_t)kc * NCH * 512;
#pragma unroll
    for (int nc = 0; nc < NCH; ++nc) {
      short8 bfr = *(const short8*)(bp + (size_t)nc * 512 + lane * 8);
      acc[nc] = __builtin_amdgcn_mfma_f32_16x16x32_bf16(af, bfr, acc[nc], 0, 0, 0);
    }
  }

  float ds[4];
#pragma unroll
  for (int r = 0; r < 4; ++r) ds[r] = dinv[row0 + q * 4 + r];
#pragma unroll
  for (int nc = 0; nc < NCH; ++nc) {
#pragma unroll
    for (int r = 0; r < 4; ++r) {
      int row = row0 + q * 4 + r;
      C[(size_t)row * N + nc * 16 + m] = f2bf(acc[nc][r] * ds[r]);
    }
  }
}

// ---------------- conv1 agg: h1'[n] = dinv[n]*relu(dn*(sum + self) + b1) ----------------
// padded uniform 8-loop; esrc via wave-uniform int4 loads

__global__ __launch_bounds__(128) void k_agg1(const unsigned* __restrict__ p,
                                              const float* __restrict__ bias,
                                              const int* __restrict__ rowptr,
                                              const int* __restrict__ esrc,
                                              const float* __restrict__ dinv,
                                              unsigned* __restrict__ out) {
  const int n = blockIdx.x * 2 + (threadIdx.x >> 6);
  const int t = threadIdx.x & 63;

  float2 f = bf2f(p[(size_t)n * 64 + t]);
  float ax = f.x, ay = f.y;  // self term xw'[n]

  const int r0 = rowptr[n];
  const int r1 = rowptr[n + 1];
  for (int i = r0; i < r1; i += 8) {
    int4 ea = *(const int4*)(esrc + i);
    int4 eb = *(const int4*)(esrc + i + 4);
    unsigned u0 = p[(size_t)ea.x * 64 + t];
    unsigned u1 = p[(size_t)ea.y * 64 + t];
    unsigned u2 = p[(size_t)ea.z * 64 + t];
    unsigned u3 = p[(size_t)ea.w * 64 + t];
    unsigned u4 = p[(size_t)eb.x * 64 + t];
    unsigned u5 = p[(size_t)eb.y * 64 + t];
    unsigned u6 = p[(size_t)eb.z * 64 + t];
    unsigned u7 = p[(size_t)eb.w * 64 + t];
    f = bf2f(u0); ax += f.x; ay += f.y;
    f = bf2f(u1); ax += f.x; ay += f.y;
    f = bf2f(u2); ax += f.x; ay += f.y;
    f = bf2f(u3); ax += f.x; ay += f.y;
    f = bf2f(u4); ax += f.x; ay += f.y;
    f = bf2f(u5); ax += f.x; ay += f.y;
    f = bf2f(u6); ax += f.x; ay += f.y;
    f = bf2f(u7); ax += f.x; ay += f.y;
  }

  const float dn = dinv[n];
  float2 bb = ((const float2*)bias)[t];
  ax = fmaf(dn, ax, bb.x);
  ay = fmaf(dn, ay, bb.y);
  ax = fmaxf(ax, 0.f) * dn;  // relu then prescale for conv2
  ay = fmaxf(ay, 0.f) * dn;
  out[(size_t)n * 64 + t] = (unsigned)f2bf(ax) | ((unsigned)f2bf(ay) << 16);
}

// ---------------- conv2 agg fused with mean-pool numerator ----------------

__global__ __launch_bounds__(128) void k_agg2(const unsigned* __restrict__ p,
                                              const int* __restrict__ rowptr,
                                              const int* __restrict__ esrc,
                                              const float* __restrict__ dinv,
                                              const int* __restrict__ batch,
                                              float* __restrict__ praw) {
  const int n = blockIdx.x * 2 + (threadIdx.x >> 6);
  const int t = threadIdx.x & 63;

  float2 f = bf2f(p[(size_t)n * 64 + t]);
  float ax = f.x, ay = f.y;  // self term h1'[n]

  const int r0 = rowptr[n];
  const int r1 = rowptr[n + 1];
  for (int i = r0; i < r1; i += 8) {
    int4 ea = *(const int4*)(esrc + i);
    int4 eb = *(const int4*)(esrc + i + 4);
    unsigned u0 = p[(size_t)ea.x * 64 + t];
    unsigned u1 = p[(size_t)ea.y * 64 + t];
    unsigned u2 = p[(size_t)ea.z * 64 + t];
    unsigned u3 = p[(size_t)ea.w * 64 + t];
    unsigned u4 = p[(size_t)eb.x * 64 + t];
    unsigned u5 = p[(size_t)eb.y * 64 + t];
    unsigned u6 = p[(size_t)eb.z * 64 + t];
    unsigned u7 = p[(size_t)eb.w * 64 + t];
    f = bf2f(u0); ax += f.x; ay += f.y;
    f = bf2f(u1); ax += f.x; ay += f.y;
    f = bf2f(u2); ax += f.x; ay += f.y;
    f = bf2f(u3); ax += f.x; ay += f.y;
    f = bf2f(u4); ax += f.x; ay += f.y;
    f = bf2f(u5); ax += f.x; ay += f.y;
    f = bf2f(u6); ax += f.x; ay += f.y;
    f = bf2f(u7); ax += f.x; ay += f.y;
  }

  const float dn = dinv[n];
  const int g = batch[n];
  atomicAdd(&praw[g * KF + 2 * t], dn * ax);
  atomicAdd(&praw[g * KF + 2 * t + 1], dn * ay);
}

// ---------------- heads: counts + mini-GEMM (praw/c @ W2 + b2) + logits ----------------

__global__ __launch_bounds__(256) void k_heads(const float* __restrict__ praw,
                                               const int* __restrict__ batch,
                                               const float* __restrict__ W2,
                                               const float* __restrict__ b2,
                                               const float* __restrict__ Wg,
                                               const float* __restrict__ bg,
                                               const float* __restrict__ Wf,
                                               const float* __restrict__ bfb,
                                               float* __restrict__ out) {
  int b = blockIdx.x;
  int t = threadIdx.x;  // 256
  __shared__ float pr[KF];
  __shared__ float p[H2F];
  __shared__ int bnd[2];
  if (t < 2) {
    int target = b + t;  // search first index with batch[] >= target
    int lo = 0, hi = NN;
    while (lo < hi) { int mid = (lo + hi) >> 1; if (batch[mid] < target) lo = mid + 1; else hi = mid; }
    bnd[t] = lo;
  }
  __syncthreads();
  float cg = fmaxf((float)(bnd[1] - bnd[0]), 1.f);
  if (t < KF) pr[t] = praw[b * KF + t] / cg;
  __syncthreads();
  float acc = b2[t];
#pragma unroll 8
  for (int d = 0; d < KF; ++d) acc = fmaf(pr[d], W2[d * H2F + t], acc);
  p[t] = acc;
  __syncthreads();
  if (t < NGRP) {
    float a = bg[t];
    for (int d = 0; d < H2F; ++d) a = fmaf(p[d], Wg[d * NGRP + t], a);
    out[b * NGRP + t] = a;
  } else if (t >= 64 && t < 64 + NGRP * NFAM) {
    int u = t - 64;
    int g = u / NFAM;
    int ff = u % NFAM;
    float a = bfb[g * NFAM + ff];
    for (int d = 0; d < H2F; ++d) a = fmaf(p[d], Wf[(g * H2F + d) * NFAM + ff], a);
    out[NGR * NGRP + (size_t)g * NGR * NFAM + b * NFAM + ff] = a;
  }
}

// ---------------- launch ----------------

extern "C" void kernel_launch(void* const* d_in, const int* in_sizes, int n_in,
                              void* d_out, int out_size, void* d_ws, size_t ws_size,
                              hipStream_t stream) {
  const float* x    = (const float*)d_in[0];
  const int*   ei   = (const int*)d_in[1];
  const int*   batch= (const int*)d_in[2];
  const float* W1   = (const float*)d_in[3];
  const float* b1   = (const float*)d_in[4];
  const float* W2   = (const float*)d_in[5];
  const float* b2   = (const float*)d_in[6];
  const float* Wg   = (const float*)d_in[7];
  const float* bg   = (const float*)d_in[8];
  const float* Wf   = (const float*)d_in[9];
  const float* bfb  = (const float*)d_in[10];
  float* out = (float*)d_out;

  char* w = (char*)d_ws;
  auto take = [&](size_t bytes) {
    char* p = w;
    w += (bytes + 255) & ~(size_t)255;
    return (void*)p;
  };
  int*   mat   = (int*)take((size_t)NT * NCHUNK * 4);
  int*   tot   = (int*)take((size_t)NCHUNK * 4);
  int*   cbase = (int*)take((size_t)(NCHUNK + 1) * 4);
  int2*  erec  = (int2*)take((size_t)NT * PT * 8);
  int*   esrc  = (int*)take(((size_t)NE + (size_t)NCHUNK * CSLACK + 16) * 4);
  int*   rowptr= (int*)take((size_t)(NN + 1) * 4);
  float* dinv  = (float*)take((size_t)NN * 4);
  float* praw  = (float*)take((size_t)NGR * KF * 4);
  unsigned short* Bp1 = (unsigned short*)take((size_t)KF * KF * 2);
  unsigned* xw1 = (unsigned*)take((size_t)(NN + 1) * KF * 2);
  unsigned* h1  = (unsigned*)take((size_t)(NN + 1) * KF * 2);

  hipMemsetAsync(praw, 0, (size_t)NGR * KF * 4, stream);

  k_phist<<<NT, 256, 0, stream>>>(ei, mat);
  k_colsum<<<(NCHUNK + 3) / 4, 256, 0, stream>>>(mat, tot);
  k_scantot<<<1, 256, 0, stream>>>(tot, cbase);
  k_colfix<<<(NCHUNK + 3) / 4, 256, 0, stream>>>(mat, cbase);
  k_pscatter<<<NT, 256, 0, stream>>>(ei, mat, erec);
  k_sort<<<NCHUNK, 256, 0, stream>>>(erec, cbase, esrc, rowptr, dinv);

  k_zero<<<1, 64, 0, stream>>>(xw1, h1);
  k_prepB<<<(KF * KF + 255) / 256, 256, 0, stream>>>(W1, Bp1, KF);
  k_gemm_mfma<<<1563, 256, 0, stream>>>(x, Bp1, dinv, (unsigned short*)xw1);

  k_agg1<<<NN / 2, 128, 0, stream>>>(xw1, b1, rowptr, esrc, dinv, h1);
  k_agg2<<<NN / 2, 128, 0, stream>>>(h1, rowptr, esrc, dinv, batch, praw);

  k_heads<<<NGR, 256, 0, stream>>>(praw, batch, W2, b2, Wg, bg, Wf, bfb, out);
}

// Round 8
// 875.357 us; speedup vs baseline: 1.0575x; 1.0575x over previous
//
#include <hip/hip_runtime.h>

#define NN 100000     // nodes
#define NE 1600000    // edges
#define NGR 512       // graphs
#define KF 128        // IN_F == H1
#define H2F 256
#define NGRP 16
#define NFAM 10

#define CH 128                          // nodes per chunk
#define NCHUNK ((NN + CH - 1) / CH)     // 782
#define PT 6656                         // edges per partition tile
#define NT ((NE + PT - 1) / PT)         // 241
#define CSLACK 1024                     // per-chunk padded slack (>= 128*7 + 8)

typedef __attribute__((ext_vector_type(8))) short short8;
typedef __attribute__((ext_vector_type(4))) float floatx4;

__device__ __forceinline__ unsigned short f2bf(float f) {
  unsigned u = __float_as_uint(f);
  unsigned r = (u + 0x7fff + ((u >> 16) & 1)) >> 16;
  return (unsigned short)r;
}
__device__ __forceinline__ float2 bf2f(unsigned u) {
  float2 r;
  r.x = __uint_as_float(u << 16);
  r.y = __uint_as_float(u & 0xffff0000u);
  return r;
}

// ---------------- edge partition by dst chunk (dst>>7), LDS-staged ----------------

__global__ __launch_bounds__(256) void k_phist(const int* __restrict__ ei,
                                               int* __restrict__ mat) {
  __shared__ int lh[NCHUNK];
  int t0 = blockIdx.x, tid = threadIdx.x;
  for (int g = tid; g < NCHUNK; g += 256) lh[g] = 0;
  __syncthreads();
  int base = t0 * PT;
  int nv = min(PT, NE - base);
  for (int i = tid; i < nv; i += 256) atomicAdd(&lh[ei[NE + base + i] >> 7], 1);
  __syncthreads();
  for (int g = tid; g < NCHUNK; g += 256) mat[t0 * NCHUNK + g] = lh[g];
}

// column sums of mat -> tot[NCHUNK]; one wave per column
__global__ __launch_bounds__(256) void k_colsum(const int* __restrict__ mat,
                                                int* __restrict__ tot) {
  int g = blockIdx.x * 4 + (threadIdx.x >> 6);
  if (g >= NCHUNK) return;
  int lane = threadIdx.x & 63;
  int s = 0;
  for (int t = lane; t < NT; t += 64) s += mat[t * NCHUNK + g];
#pragma unroll
  for (int off = 32; off > 0; off >>= 1) s += __shfl_down(s, off);
  if (lane == 0) tot[g] = s;
}

// exclusive scan of tot[NCHUNK] -> cbase
__global__ __launch_bounds__(256) void k_scantot(const int* __restrict__ tot,
                                                 int* __restrict__ cbase) {
  __shared__ int ssc[256];
  int tid = threadIdx.x;
  int v4[4]; int loc = 0;
#pragma unroll
  for (int j = 0; j < 4; ++j) {
    int idx = tid * 4 + j;
    v4[j] = (idx < NCHUNK) ? tot[idx] : 0;
    loc += v4[j];
  }
  ssc[tid] = loc;
  __syncthreads();
  for (int off = 1; off < 256; off <<= 1) {
    int val = (tid >= off) ? ssc[tid - off] : 0;
    __syncthreads();
    ssc[tid] += val;
    __syncthreads();
  }
  int excl = ssc[tid] - loc;
#pragma unroll
  for (int j = 0; j < 4; ++j) {
    int idx = tid * 4 + j;
    if (idx < NCHUNK) cbase[idx] = excl;
    excl += v4[j];
  }
  if (tid == 255) cbase[NCHUNK] = excl;  // == NE
}

// per-column prefix over tiles; one wave/column
__global__ __launch_bounds__(256) void k_colfix(int* __restrict__ mat,
                                                const int* __restrict__ cbase) {
  int g = blockIdx.x * 4 + (threadIdx.x >> 6);
  if (g >= NCHUNK) return;
  int lane = threadIdx.x & 63;
  int v[4]; int loc = 0;
#pragma unroll
  for (int j = 0; j < 4; ++j) {
    int t = lane * 4 + j;
    v[j] = (t < NT) ? mat[t * NCHUNK + g] : 0;
    loc += v[j];
  }
  int incl = loc;
#pragma unroll
  for (int off = 1; off < 64; off <<= 1) {
    int o = __shfl_up(incl, off);
    if (lane >= off) incl += o;
  }
  int excl = incl - loc + cbase[g];
#pragma unroll
  for (int j = 0; j < 4; ++j) {
    int t = lane * 4 + j;
    if (t < NT) mat[t * NCHUNK + g] = excl;
    excl += v[j];
  }
}

__global__ __launch_bounds__(256) void k_pscatter(const int* __restrict__ ei,
                                                  const int* __restrict__ mat,
                                                  int2* __restrict__ erec) {
  __shared__ int2 stage[PT];
  __shared__ int lstart[NCHUNK];
  __shared__ int lrun[NCHUNK];
  __shared__ int loff[NCHUNK];
  __shared__ int ssc[256];
  int t0 = blockIdx.x, tid = threadIdx.x;
  for (int g = tid; g < NCHUNK; g += 256) lrun[g] = 0;
  __syncthreads();
  int base = t0 * PT;
  int nv = min(PT, NE - base);
  for (int i = tid; i < nv; i += 256) atomicAdd(&lrun[ei[NE + base + i] >> 7], 1);
  __syncthreads();
  int v4[4]; int loc = 0;
#pragma unroll
  for (int j = 0; j < 4; ++j) {
    int idx = tid * 4 + j;
    v4[j] = (idx < NCHUNK) ? lrun[idx] : 0;
    loc += v4[j];
  }
  ssc[tid] = loc;
  __syncthreads();
  for (int off = 1; off < 256; off <<= 1) {
    int val = (tid >= off) ? ssc[tid - off] : 0;
    __syncthreads();
    ssc[tid] += val;
    __syncthreads();
  }
  int excl = ssc[tid] - loc;
#pragma unroll
  for (int j = 0; j < 4; ++j) {
    int idx = tid * 4 + j;
    if (idx < NCHUNK) lstart[idx] = excl;
    excl += v4[j];
  }
  __syncthreads();
  for (int g = tid; g < NCHUNK; g += 256) {
    lrun[g] = lstart[g];
    loff[g] = mat[t0 * NCHUNK + g];
  }
  __syncthreads();
  for (int i = tid; i < nv; i += 256) {
    int s = ei[base + i], d = ei[NE + base + i];
    int pos = atomicAdd(&lrun[d >> 7], 1);
    stage[pos] = make_int2(s, d);
  }
  __syncthreads();
  for (int j = tid; j < nv; j += 256) {
    int2 r = stage[j];
    int g = r.y >> 7;
    erec[loff[g] + (j - lstart[g])] = r;
  }
}

// ---------------- per-chunk counting sort into padded per-node runs ----------------
// Each node's run padded to x8 with dummy src NN (zero row).

__global__ __launch_bounds__(256) void k_sort(const int2* __restrict__ erec,
                                              const int* __restrict__ cbase,
                                              int* __restrict__ esrc,
                                              int* __restrict__ rowptr,
                                              float* __restrict__ dinv) {
  __shared__ int hist[CH];
  __shared__ int lrun[CH];
  __shared__ int sc[256];
  const int c = blockIdx.x, tid = threadIdx.x;
  const int e0 = cbase[c], e1 = cbase[c + 1];
  const int nv = e1 - e0;
  const int pb = ((e0 + 7) & ~7) + c * CSLACK;
  const int pe = ((e1 + 7) & ~7) + (c + 1) * CSLACK;
  if (tid < CH) hist[tid] = 0;
  __syncthreads();
  for (int i = tid; i < nv; i += 256) atomicAdd(&hist[erec[e0 + i].y & (CH - 1)], 1);
  __syncthreads();
  int deg = (tid < CH) ? hist[tid] : 0;
  int pd = (deg + 7) & ~7;
  sc[tid] = pd;
  __syncthreads();
  for (int off = 1; off < 256; off <<= 1) {
    int val = (tid >= off) ? sc[tid - off] : 0;
    __syncthreads();
    sc[tid] += val;
    __syncthreads();
  }
  int excl = sc[tid] - pd;
  int node = c * CH + tid;
  if (tid < CH) {
    lrun[tid] = excl;
    if (node < NN) {
      rowptr[node] = pb + excl;
      dinv[node] = rsqrtf((float)(deg + 1));  // +1 self loop
    }
    if (node == NN) rowptr[NN] = pb + excl;
  }
  __syncthreads();
  for (int i = pb + tid; i < pe; i += 256) esrc[i] = NN;  // dummy fill
  __syncthreads();
  for (int i = tid; i < nv; i += 256) {
    int2 r = erec[e0 + i];
    int pos = atomicAdd(&lrun[r.y & (CH - 1)], 1);
    esrc[pb + pos] = r.x;
  }
}

// ---------------- zero the dummy rows (index NN) of xw1' and h1' ----------------

__global__ void k_zero(unsigned* __restrict__ a, unsigned* __restrict__ b) {
  int t = threadIdx.x;  // 64
  a[(size_t)NN * 64 + t] = 0;
  b[(size_t)NN * 64 + t] = 0;
}

// ---------------- W1 pre-swizzle into MFMA B-fragment layout ----------------

__global__ void k_prepB(const float* __restrict__ W, unsigned short* __restrict__ Bp,
                        int Ncol) {
  int idx = blockIdx.x * 256 + threadIdx.x;
  int total = 128 * Ncol;
  if (idx >= total) return;
  int NCH = Ncol >> 4;
  int j = idx & 7;
  int l = (idx >> 3) & 63;
  int rest = idx >> 9;
  int nc = rest % NCH;
  int kc = rest / NCH;
  int k = kc * 32 + (l >> 4) * 8 + j;
  int nn = nc * 16 + (l & 15);
  Bp[idx] = f2bf(W[k * Ncol + nn]);
}

// ---------------- MFMA GEMM1: xw1'[n] = dinv[n] * (x[n] @ W1), bf16 out ----------------

__global__ __launch_bounds__(256) void k_gemm_mfma(const float* __restrict__ A,
                                                   const unsigned short* __restrict__ Bp,
                                                   const float* __restrict__ dinv,
                                                   unsigned short* __restrict__ C) {
  constexpr int K = 128;
  constexpr int N = KF;
  constexpr int NCH = N / 16;
  const int wv = blockIdx.x * 4 + (threadIdx.x >> 6);
  const int row0 = wv * 16;
  if (row0 >= NN) return;  // 100000 % 16 == 0
  const int lane = threadIdx.x & 63;
  const int m = lane & 15;
  const int q = lane >> 4;

  floatx4 acc[NCH];
#pragma unroll
  for (int i = 0; i < NCH; ++i) acc[i] = (floatx4){0.f, 0.f, 0.f, 0.f};

  const int arow = row0 + m;
#pragma unroll
  for (int kc = 0; kc < 4; ++kc) {
    const float* ap = A + (size_t)arow * K + kc * 32 + q * 8;
    float4 f0 = *(const float4*)ap;
    float4 f1 = *(const float4*)(ap + 4);
    short8 af;
    af[0] = (short)f2bf(f0.x); af[1] = (short)f2bf(f0.y);
    af[2] = (short)f2bf(f0.z); af[3] = (short)f2bf(f0.w);
    af[4] = (short)f2bf(f1.x); af[5] = (short)f2bf(f1.y);
    af[6] = (short)f2bf(f1.z); af[7] = (short)f2bf(f1.w);
    const unsigned short* bp = Bp + (size_t)kc * NCH * 512;
#pragma unroll
    for (int nc = 0; nc < NCH; ++nc) {
      short8 bfr = *(const short8*)(bp + (size_t)nc * 512 + lane * 8);
      acc[nc] = __builtin_amdgcn_mfma_f32_16x16x32_bf16(af, bfr, acc[nc], 0, 0, 0);
    }
  }

  float ds[4];
#pragma unroll
  for (int r = 0; r < 4; ++r) ds[r] = dinv[row0 + q * 4 + r];
#pragma unroll
  for (int nc = 0; nc < NCH; ++nc) {
#pragma unroll
    for (int r = 0; r < 4; ++r) {
      int row = row0 + q * 4 + r;
      C[(size_t)row * N + nc * 16 + m] = f2bf(acc[nc][r] * ds[r]);
    }
  }
}

// ---------------- conv1 agg: h1'[n] = dinv[n]*relu(dn*(sum + self) + b1) ----------------
// padded uniform 8-loop; esrc via wave-uniform int4 loads

__global__ __launch_bounds__(128) void k_agg1(const unsigned* __restrict__ p,
                                              const float* __restrict__ bias,
                                              const int* __restrict__ rowptr,
                                              const int* __restrict__ esrc,
                                              const float* __restrict__ dinv,
                                              unsigned* __restrict__ out) {
  const int n = blockIdx.x * 2 + (threadIdx.x >> 6);
  const int t = threadIdx.x & 63;

  float2 f = bf2f(p[(size_t)n * 64 + t]);
  float ax = f.x, ay = f.y;  // self term xw'[n]

  const int r0 = rowptr[n];
  const int r1 = rowptr[n + 1];
  for (int i = r0; i < r1; i += 8) {
    int4 ea = *(const int4*)(esrc + i);
    int4 eb = *(const int4*)(esrc + i + 4);
    unsigned u0 = p[(size_t)ea.x * 64 + t];
    unsigned u1 = p[(size_t)ea.y * 64 + t];
    unsigned u2 = p[(size_t)ea.z * 64 + t];
    unsigned u3 = p[(size_t)ea.w * 64 + t];
    unsigned u4 = p[(size_t)eb.x * 64 + t];
    unsigned u5 = p[(size_t)eb.y * 64 + t];
    unsigned u6 = p[(size_t)eb.z * 64 + t];
    unsigned u7 = p[(size_t)eb.w * 64 + t];
    f = bf2f(u0); ax += f.x; ay += f.y;
    f = bf2f(u1); ax += f.x; ay += f.y;
    f = bf2f(u2); ax += f.x; ay += f.y;
    f = bf2f(u3); ax += f.x; ay += f.y;
    f = bf2f(u4); ax += f.x; ay += f.y;
    f = bf2f(u5); ax += f.x; ay += f.y;
    f = bf2f(u6); ax += f.x; ay += f.y;
    f = bf2f(u7); ax += f.x; ay += f.y;
  }

  const float dn = dinv[n];
  float2 bb = ((const float2*)bias)[t];
  ax = fmaf(dn, ax, bb.x);
  ay = fmaf(dn, ay, bb.y);
  ax = fmaxf(ax, 0.f) * dn;  // relu then prescale for conv2
  ay = fmaxf(ay, 0.f) * dn;
  out[(size_t)n * 64 + t] = (unsigned)f2bf(ax) | ((unsigned)f2bf(ay) << 16);
}

// ---------------- conv2 agg: agg2[n] = dinv[n]*(sum + self), bf16 store ----------------

__global__ __launch_bounds__(128) void k_agg2(const unsigned* __restrict__ p,
                                              const int* __restrict__ rowptr,
                                              const int* __restrict__ esrc,
                                              const float* __restrict__ dinv,
                                              unsigned* __restrict__ out) {
  const int n = blockIdx.x * 2 + (threadIdx.x >> 6);
  const int t = threadIdx.x & 63;

  float2 f = bf2f(p[(size_t)n * 64 + t]);
  float ax = f.x, ay = f.y;  // self term h1'[n]

  const int r0 = rowptr[n];
  const int r1 = rowptr[n + 1];
  for (int i = r0; i < r1; i += 8) {
    int4 ea = *(const int4*)(esrc + i);
    int4 eb = *(const int4*)(esrc + i + 4);
    unsigned u0 = p[(size_t)ea.x * 64 + t];
    unsigned u1 = p[(size_t)ea.y * 64 + t];
    unsigned u2 = p[(size_t)ea.z * 64 + t];
    unsigned u3 = p[(size_t)ea.w * 64 + t];
    unsigned u4 = p[(size_t)eb.x * 64 + t];
    unsigned u5 = p[(size_t)eb.y * 64 + t];
    unsigned u6 = p[(size_t)eb.z * 64 + t];
    unsigned u7 = p[(size_t)eb.w * 64 + t];
    f = bf2f(u0); ax += f.x; ay += f.y;
    f = bf2f(u1); ax += f.x; ay += f.y;
    f = bf2f(u2); ax += f.x; ay += f.y;
    f = bf2f(u3); ax += f.x; ay += f.y;
    f = bf2f(u4); ax += f.x; ay += f.y;
    f = bf2f(u5); ax += f.x; ay += f.y;
    f = bf2f(u6); ax += f.x; ay += f.y;
    f = bf2f(u7); ax += f.x; ay += f.y;
  }

  const float dn = dinv[n];
  out[(size_t)n * 64 + t] = (unsigned)f2bf(dn * ax) | ((unsigned)f2bf(dn * ay) << 16);
}

// ---------------- mean pool over sorted batch (F=128, bf16 in, f32 out) ----------------

__global__ __launch_bounds__(256) void k_pool(const unsigned* __restrict__ p,
                                              const int* __restrict__ batch,
                                              float* __restrict__ pooled_raw) {
  int g = blockIdx.x;
  int t = threadIdx.x & 63;   // feature uint (2 bf16)
  int wv = threadIdx.x >> 6;  // 4 waves split the node range
  int lo = 0, hi = NN;
  while (lo < hi) { int mid = (lo + hi) >> 1; if (batch[mid] < g) lo = mid + 1; else hi = mid; }
  int start = lo;
  hi = NN;
  while (lo < hi) { int mid = (lo + hi) >> 1; if (batch[mid] < g + 1) lo = mid + 1; else hi = mid; }
  int end = lo;

  float sx = 0.f, sy = 0.f;
  int n = start + wv;
  for (; n + 12 < end; n += 16) {
    unsigned u0 = p[(size_t)n * 64 + t];
    unsigned u1 = p[(size_t)(n + 4) * 64 + t];
    unsigned u2 = p[(size_t)(n + 8) * 64 + t];
    unsigned u3 = p[(size_t)(n + 12) * 64 + t];
    float2 f0 = bf2f(u0), f1 = bf2f(u1), f2 = bf2f(u2), f3 = bf2f(u3);
    sx += (f0.x + f1.x) + (f2.x + f3.x);
    sy += (f0.y + f1.y) + (f2.y + f3.y);
  }
  for (; n < end; n += 4) {
    float2 f = bf2f(p[(size_t)n * 64 + t]);
    sx += f.x; sy += f.y;
  }

  __shared__ float sh[4][128];
  sh[wv][2 * t] = sx;
  sh[wv][2 * t + 1] = sy;
  __syncthreads();
  if (wv == 0) {
    float vx = sh[0][2 * t] + sh[1][2 * t] + sh[2][2 * t] + sh[3][2 * t];
    float vy = sh[0][2 * t + 1] + sh[1][2 * t + 1] + sh[2][2 * t + 1] + sh[3][2 * t + 1];
    float c = fmaxf((float)(end - start), 1.f);
    pooled_raw[g * KF + 2 * t] = vx / c;
    pooled_raw[g * KF + 2 * t + 1] = vy / c;
  }
}

// ---------------- fused mini-GEMM (pooled = praw @ W2 + b2) + heads ----------------

__global__ __launch_bounds__(256) void k_heads(const float* __restrict__ praw,
                                               const float* __restrict__ W2,
                                               const float* __restrict__ b2,
                                               const float* __restrict__ Wg,
                                               const float* __restrict__ bg,
                                               const float* __restrict__ Wf,
                                               const float* __restrict__ bfb,
                                               float* __restrict__ out) {
  int b = blockIdx.x;
  int t = threadIdx.x;  // 256
  __shared__ float pr[KF];
  __shared__ float p[H2F];
  if (t < KF) pr[t] = praw[b * KF + t];
  __syncthreads();
  float acc = b2[t];
#pragma unroll 8
  for (int d = 0; d < KF; ++d) acc = fmaf(pr[d], W2[d * H2F + t], acc);
  p[t] = acc;
  __syncthreads();
  if (t < NGRP) {
    float a = bg[t];
    for (int d = 0; d < H2F; ++d) a = fmaf(p[d], Wg[d * NGRP + t], a);
    out[b * NGRP + t] = a;
  } else if (t >= 64 && t < 64 + NGRP * NFAM) {
    int u = t - 64;
    int g = u / NFAM;
    int ff = u % NFAM;
    float a = bfb[g * NFAM + ff];
    for (int d = 0; d < H2F; ++d) a = fmaf(p[d], Wf[(g * H2F + d) * NFAM + ff], a);
    out[NGR * NGRP + (size_t)g * NGR * NFAM + b * NFAM + ff] = a;
  }
}

// ---------------- launch ----------------

extern "C" void kernel_launch(void* const* d_in, const int* in_sizes, int n_in,
                              void* d_out, int out_size, void* d_ws, size_t ws_size,
                              hipStream_t stream) {
  const float* x    = (const float*)d_in[0];
  const int*   ei   = (const int*)d_in[1];
  const int*   batch= (const int*)d_in[2];
  const float* W1   = (const float*)d_in[3];
  const float* b1   = (const float*)d_in[4];
  const float* W2   = (const float*)d_in[5];
  const float* b2   = (const float*)d_in[6];
  const float* Wg   = (const float*)d_in[7];
  const float* bg   = (const float*)d_in[8];
  const float* Wf   = (const float*)d_in[9];
  const float* bfb  = (const float*)d_in[10];
  float* out = (float*)d_out;

  char* w = (char*)d_ws;
  auto take = [&](size_t bytes) {
    char* p = w;
    w += (bytes + 255) & ~(size_t)255;
    return (void*)p;
  };
  int*   mat   = (int*)take((size_t)NT * NCHUNK * 4);
  int*   tot   = (int*)take((size_t)NCHUNK * 4);
  int*   cbase = (int*)take((size_t)(NCHUNK + 1) * 4);
  int2*  erec  = (int2*)take((size_t)NT * PT * 8);
  int*   esrc  = (int*)take(((size_t)NE + (size_t)NCHUNK * CSLACK + 16) * 4);
  int*   rowptr= (int*)take((size_t)(NN + 1) * 4);
  float* dinv  = (float*)take((size_t)NN * 4);
  float* praw  = (float*)take((size_t)NGR * KF * 4);
  unsigned short* Bp1 = (unsigned short*)take((size_t)KF * KF * 2);
  unsigned* xw1 = (unsigned*)take((size_t)(NN + 1) * KF * 2);
  unsigned* h1  = (unsigned*)take((size_t)(NN + 1) * KF * 2);
  unsigned* agg2= (unsigned*)take((size_t)NN * KF * 2);

  k_phist<<<NT, 256, 0, stream>>>(ei, mat);
  k_colsum<<<(NCHUNK + 3) / 4, 256, 0, stream>>>(mat, tot);
  k_scantot<<<1, 256, 0, stream>>>(tot, cbase);
  k_colfix<<<(NCHUNK + 3) / 4, 256, 0, stream>>>(mat, cbase);
  k_pscatter<<<NT, 256, 0, stream>>>(ei, mat, erec);
  k_sort<<<NCHUNK, 256, 0, stream>>>(erec, cbase, esrc, rowptr, dinv);

  k_zero<<<1, 64, 0, stream>>>(xw1, h1);
  k_prepB<<<(KF * KF + 255) / 256, 256, 0, stream>>>(W1, Bp1, KF);
  k_gemm_mfma<<<1563, 256, 0, stream>>>(x, Bp1, dinv, (unsigned short*)xw1);

  k_agg1<<<NN / 2, 128, 0, stream>>>(xw1, b1, rowptr, esrc, dinv, h1);
  k_agg2<<<NN / 2, 128, 0, stream>>>(h1, rowptr, esrc, dinv, agg2);

  k_pool<<<NGR, 256, 0, stream>>>(agg2, batch, praw);
  k_heads<<<NGR, 256, 0, stream>>>(praw, W2, b2, Wg, bg, Wf, bfb, out);
}

// Round 9
// 347.898 us; speedup vs baseline: 2.6608x; 2.5161x over previous
//
#include <hip/hip_runtime.h>

#define NN 100000     // nodes
#define NE 1600000    // edges
#define NGR 512       // graphs
#define KF 128        // IN_F == H1
#define H2F 256
#define NGRP 16
#define NFAM 10

#define CH 128                          // nodes per chunk
#define NCHUNK ((NN + CH - 1) / CH)     // 782
#define PT 6656                         // edges per partition tile
#define NT ((NE + PT - 1) / PT)         // 241

typedef __attribute__((ext_vector_type(8))) short short8;
typedef __attribute__((ext_vector_type(4))) float floatx4;

__device__ __forceinline__ unsigned short f2bf(float f) {
  unsigned u = __float_as_uint(f);
  unsigned r = (u + 0x7fff + ((u >> 16) & 1)) >> 16;
  return (unsigned short)r;
}
__device__ __forceinline__ float2 bf2f(unsigned u) {
  float2 r;
  r.x = __uint_as_float(u << 16);
  r.y = __uint_as_float(u & 0xffff0000u);
  return r;
}

// ---------------- edge partition by dst chunk (dst>>7), LDS-staged ----------------

__global__ __launch_bounds__(256) void k_phist(const int* __restrict__ ei,
                                               int* __restrict__ mat) {
  __shared__ int lh[NCHUNK];
  int t0 = blockIdx.x, tid = threadIdx.x;
  for (int g = tid; g < NCHUNK; g += 256) lh[g] = 0;
  __syncthreads();
  int base = t0 * PT;
  int nv = min(PT, NE - base);
  for (int i = tid; i < nv; i += 256) atomicAdd(&lh[ei[NE + base + i] >> 7], 1);
  __syncthreads();
  for (int g = tid; g < NCHUNK; g += 256) mat[t0 * NCHUNK + g] = lh[g];
}

// column sums of mat -> tot[NCHUNK]; one wave per column
__global__ __launch_bounds__(256) void k_colsum(const int* __restrict__ mat,
                                                int* __restrict__ tot) {
  int g = blockIdx.x * 4 + (threadIdx.x >> 6);
  if (g >= NCHUNK) return;
  int lane = threadIdx.x & 63;
  int s = 0;
  for (int t = lane; t < NT; t += 64) s += mat[t * NCHUNK + g];
#pragma unroll
  for (int off = 32; off > 0; off >>= 1) s += __shfl_down(s, off);
  if (lane == 0) tot[g] = s;
}

// exclusive scan of tot[NCHUNK] -> cbase
__global__ __launch_bounds__(256) void k_scantot(const int* __restrict__ tot,
                                                 int* __restrict__ cbase) {
  __shared__ int ssc[256];
  int tid = threadIdx.x;
  int v4[4]; int loc = 0;
#pragma unroll
  for (int j = 0; j < 4; ++j) {
    int idx = tid * 4 + j;
    v4[j] = (idx < NCHUNK) ? tot[idx] : 0;
    loc += v4[j];
  }
  ssc[tid] = loc;
  __syncthreads();
  for (int off = 1; off < 256; off <<= 1) {
    int val = (tid >= off) ? ssc[tid - off] : 0;
    __syncthreads();
    ssc[tid] += val;
    __syncthreads();
  }
  int excl = ssc[tid] - loc;
#pragma unroll
  for (int j = 0; j < 4; ++j) {
    int idx = tid * 4 + j;
    if (idx < NCHUNK) cbase[idx] = excl;
    excl += v4[j];
  }
  if (tid == 255) cbase[NCHUNK] = excl;  // == NE
}

// per-column prefix over tiles; one wave/column
__global__ __launch_bounds__(256) void k_colfix(int* __restrict__ mat,
                                                const int* __restrict__ cbase) {
  int g = blockIdx.x * 4 + (threadIdx.x >> 6);
  if (g >= NCHUNK) return;
  int lane = threadIdx.x & 63;
  int v[4]; int loc = 0;
#pragma unroll
  for (int j = 0; j < 4; ++j) {
    int t = lane * 4 + j;
    v[j] = (t < NT) ? mat[t * NCHUNK + g] : 0;
    loc += v[j];
  }
  int incl = loc;
#pragma unroll
  for (int off = 1; off < 64; off <<= 1) {
    int o = __shfl_up(incl, off);
    if (lane >= off) incl += o;
  }
  int excl = incl - loc + cbase[g];
#pragma unroll
  for (int j = 0; j < 4; ++j) {
    int t = lane * 4 + j;
    if (t < NT) mat[t * NCHUNK + g] = excl;
    excl += v[j];
  }
}

__global__ __launch_bounds__(256) void k_pscatter(const int* __restrict__ ei,
                                                  const int* __restrict__ mat,
                                                  int2* __restrict__ erec) {
  __shared__ int2 stage[PT];
  __shared__ int lstart[NCHUNK];
  __shared__ int lrun[NCHUNK];
  __shared__ int loff[NCHUNK];
  __shared__ int ssc[256];
  int t0 = blockIdx.x, tid = threadIdx.x;
  for (int g = tid; g < NCHUNK; g += 256) lrun[g] = 0;
  __syncthreads();
  int base = t0 * PT;
  int nv = min(PT, NE - base);
  for (int i = tid; i < nv; i += 256) atomicAdd(&lrun[ei[NE + base + i] >> 7], 1);
  __syncthreads();
  int v4[4]; int loc = 0;
#pragma unroll
  for (int j = 0; j < 4; ++j) {
    int idx = tid * 4 + j;
    v4[j] = (idx < NCHUNK) ? lrun[idx] : 0;
    loc += v4[j];
  }
  ssc[tid] = loc;
  __syncthreads();
  for (int off = 1; off < 256; off <<= 1) {
    int val = (tid >= off) ? ssc[tid - off] : 0;
    __syncthreads();
    ssc[tid] += val;
    __syncthreads();
  }
  int excl = ssc[tid] - loc;
#pragma unroll
  for (int j = 0; j < 4; ++j) {
    int idx = tid * 4 + j;
    if (idx < NCHUNK) lstart[idx] = excl;
    excl += v4[j];
  }
  __syncthreads();
  for (int g = tid; g < NCHUNK; g += 256) {
    lrun[g] = lstart[g];
    loff[g] = mat[t0 * NCHUNK + g];
  }
  __syncthreads();
  for (int i = tid; i < nv; i += 256) {
    int s = ei[base + i], d = ei[NE + base + i];
    int pos = atomicAdd(&lrun[d >> 7], 1);
    stage[pos] = make_int2(s, d);
  }
  __syncthreads();
  for (int j = tid; j < nv; j += 256) {
    int2 r = stage[j];
    int g = r.y >> 7;
    erec[loff[g] + (j - lstart[g])] = r;
  }
}

// ---------------- per-chunk counting sort into packed per-node runs (+dinv) ----------------

__global__ __launch_bounds__(256) void k_sort(const int2* __restrict__ erec,
                                              const int* __restrict__ cbase,
                                              int* __restrict__ esrc,
                                              int* __restrict__ rowptr,
                                              float* __restrict__ dinv) {
  __shared__ int hist[CH];
  __shared__ int lrun[CH];
  __shared__ int sc[256];
  const int c = blockIdx.x, tid = threadIdx.x;
  const int e0 = cbase[c], e1 = cbase[c + 1];
  const int nv = e1 - e0;
  if (tid < CH) hist[tid] = 0;
  __syncthreads();
  for (int i = tid; i < nv; i += 256) atomicAdd(&hist[erec[e0 + i].y & (CH - 1)], 1);
  __syncthreads();
  int deg = (tid < CH) ? hist[tid] : 0;
  sc[tid] = deg;
  __syncthreads();
  for (int off = 1; off < 256; off <<= 1) {
    int val = (tid >= off) ? sc[tid - off] : 0;
    __syncthreads();
    sc[tid] += val;
    __syncthreads();
  }
  int excl = sc[tid] - deg;
  int node = c * CH + tid;
  if (tid < CH) {
    lrun[tid] = excl;
    if (node < NN) {
      rowptr[node] = e0 + excl;
      dinv[node] = rsqrtf((float)(deg + 1));  // in-degree + self loop
    } else if (node == NN) {
      rowptr[NN] = e0 + excl;  // == NE (last chunk)
    }
  }
  __syncthreads();
  for (int i = tid; i < nv; i += 256) {
    int2 r = erec[e0 + i];
    int pos = atomicAdd(&lrun[r.y & (CH - 1)], 1);
    esrc[e0 + pos] = r.x;
  }
}

// ---------------- W1 pre-swizzle into MFMA B-fragment layout ----------------

__global__ void k_prepB(const float* __restrict__ W, unsigned short* __restrict__ Bp,
                        int Ncol) {
  int idx = blockIdx.x * 256 + threadIdx.x;
  int total = 128 * Ncol;
  if (idx >= total) return;
  int NCH = Ncol >> 4;
  int j = idx & 7;
  int l = (idx >> 3) & 63;
  int rest = idx >> 9;
  int nc = rest % NCH;
  int kc = rest / NCH;
  int k = kc * 32 + (l >> 4) * 8 + j;
  int nn = nc * 16 + (l & 15);
  Bp[idx] = f2bf(W[k * Ncol + nn]);
}

// ---------------- MFMA GEMM1: xw1'[n] = dinv[n] * (x[n] @ W1), bf16 out ----------------

__global__ __launch_bounds__(256) void k_gemm_mfma(const float* __restrict__ A,
                                                   const unsigned short* __restrict__ Bp,
                                                   const float* __restrict__ dinv,
                                                   unsigned short* __restrict__ C) {
  constexpr int K = 128;
  constexpr int N = KF;
  constexpr int NCH = N / 16;
  const int wv = blockIdx.x * 4 + (threadIdx.x >> 6);
  const int row0 = wv * 16;
  if (row0 >= NN) return;  // 100000 % 16 == 0
  const int lane = threadIdx.x & 63;
  const int m = lane & 15;
  const int q = lane >> 4;

  floatx4 acc[NCH];
#pragma unroll
  for (int i = 0; i < NCH; ++i) acc[i] = (floatx4){0.f, 0.f, 0.f, 0.f};

  const int arow = row0 + m;
#pragma unroll
  for (int kc = 0; kc < 4; ++kc) {
    const float* ap = A + (size_t)arow * K + kc * 32 + q * 8;
    float4 f0 = *(const float4*)ap;
    float4 f1 = *(const float4*)(ap + 4);
    short8 af;
    af[0] = (short)f2bf(f0.x); af[1] = (short)f2bf(f0.y);
    af[2] = (short)f2bf(f0.z); af[3] = (short)f2bf(f0.w);
    af[4] = (short)f2bf(f1.x); af[5] = (short)f2bf(f1.y);
    af[6] = (short)f2bf(f1.z); af[7] = (short)f2bf(f1.w);
    const unsigned short* bp = Bp + (size_t)kc * NCH * 512;
#pragma unroll
    for (int nc = 0; nc < NCH; ++nc) {
      short8 bfr = *(const short8*)(bp + (size_t)nc * 512 + lane * 8);
      acc[nc] = __builtin_amdgcn_mfma_f32_16x16x32_bf16(af, bfr, acc[nc], 0, 0, 0);
    }
  }

  float ds[4];
#pragma unroll
  for (int r = 0; r < 4; ++r) ds[r] = dinv[row0 + q * 4 + r];
#pragma unroll
  for (int nc = 0; nc < NCH; ++nc) {
#pragma unroll
    for (int r = 0; r < 4; ++r) {
      int row = row0 + q * 4 + r;
      C[(size_t)row * N + nc * 16 + m] = f2bf(acc[nc][r] * ds[r]);
    }
  }
}

// ---------------- aggregation (R6 loop shape, prescaled inputs) ----------------
// agg1: h1'[n] = dinv[n] * relu( dinv[n]*(sum_s xw'[s] + xw'[n]) + b1 )
// agg2: out[n] = dinv[n] * (sum_s h1'[s] + h1'[n])

template <bool FIRST>
__global__ __launch_bounds__(128) void k_agg(const unsigned* __restrict__ p,
                                             const float* __restrict__ bias,
                                             const int* __restrict__ rowptr,
                                             const int* __restrict__ esrc,
                                             const float* __restrict__ dinv,
                                             unsigned* __restrict__ out) {
  const int n = blockIdx.x * 2 + (threadIdx.x >> 6);
  const int t = threadIdx.x & 63;

  float2 f = bf2f(p[(size_t)n * 64 + t]);
  float ax = f.x, ay = f.y;  // self term (prescaled input)

  const int r0 = rowptr[n];
  const int r1 = rowptr[n + 1];
  int i = r0;
  for (; i + 8 <= r1; i += 8) {
    int s0 = esrc[i], s1 = esrc[i + 1], s2 = esrc[i + 2], s3 = esrc[i + 3];
    int s4 = esrc[i + 4], s5 = esrc[i + 5], s6 = esrc[i + 6], s7 = esrc[i + 7];
    unsigned u0 = p[(size_t)s0 * 64 + t];
    unsigned u1 = p[(size_t)s1 * 64 + t];
    unsigned u2 = p[(size_t)s2 * 64 + t];
    unsigned u3 = p[(size_t)s3 * 64 + t];
    unsigned u4 = p[(size_t)s4 * 64 + t];
    unsigned u5 = p[(size_t)s5 * 64 + t];
    unsigned u6 = p[(size_t)s6 * 64 + t];
    unsigned u7 = p[(size_t)s7 * 64 + t];
    f = bf2f(u0); ax += f.x; ay += f.y;
    f = bf2f(u1); ax += f.x; ay += f.y;
    f = bf2f(u2); ax += f.x; ay += f.y;
    f = bf2f(u3); ax += f.x; ay += f.y;
    f = bf2f(u4); ax += f.x; ay += f.y;
    f = bf2f(u5); ax += f.x; ay += f.y;
    f = bf2f(u6); ax += f.x; ay += f.y;
    f = bf2f(u7); ax += f.x; ay += f.y;
  }
  for (; i + 4 <= r1; i += 4) {
    int s0 = esrc[i], s1 = esrc[i + 1], s2 = esrc[i + 2], s3 = esrc[i + 3];
    unsigned u0 = p[(size_t)s0 * 64 + t];
    unsigned u1 = p[(size_t)s1 * 64 + t];
    unsigned u2 = p[(size_t)s2 * 64 + t];
    unsigned u3 = p[(size_t)s3 * 64 + t];
    f = bf2f(u0); ax += f.x; ay += f.y;
    f = bf2f(u1); ax += f.x; ay += f.y;
    f = bf2f(u2); ax += f.x; ay += f.y;
    f = bf2f(u3); ax += f.x; ay += f.y;
  }
  for (; i < r1; ++i) {
    int s = esrc[i];
    f = bf2f(p[(size_t)s * 64 + t]);
    ax += f.x; ay += f.y;
  }

  const float dn = dinv[n];
  if (FIRST) {
    float2 bb = ((const float2*)bias)[t];
    ax = fmaf(dn, ax, bb.x);
    ay = fmaf(dn, ay, bb.y);
    ax = fmaxf(ax, 0.f) * dn;  // relu then prescale for conv2
    ay = fmaxf(ay, 0.f) * dn;
  } else {
    ax *= dn;
    ay *= dn;
  }
  out[(size_t)n * 64 + t] = (unsigned)f2bf(ax) | ((unsigned)f2bf(ay) << 16);
}

// ---------------- mean pool over sorted batch (F=128, bf16 in, f32 out) ----------------

__global__ __launch_bounds__(256) void k_pool(const unsigned* __restrict__ p,
                                              const int* __restrict__ batch,
                                              float* __restrict__ pooled_raw) {
  int g = blockIdx.x;
  int t = threadIdx.x & 63;   // feature uint (2 bf16)
  int wv = threadIdx.x >> 6;  // 4 waves split the node range
  int lo = 0, hi = NN;
  while (lo < hi) { int mid = (lo + hi) >> 1; if (batch[mid] < g) lo = mid + 1; else hi = mid; }
  int start = lo;
  hi = NN;
  while (lo < hi) { int mid = (lo + hi) >> 1; if (batch[mid] < g + 1) lo = mid + 1; else hi = mid; }
  int end = lo;

  float sx = 0.f, sy = 0.f;
  int n = start + wv;
  for (; n + 12 < end; n += 16) {
    unsigned u0 = p[(size_t)n * 64 + t];
    unsigned u1 = p[(size_t)(n + 4) * 64 + t];
    unsigned u2 = p[(size_t)(n + 8) * 64 + t];
    unsigned u3 = p[(size_t)(n + 12) * 64 + t];
    float2 f0 = bf2f(u0), f1 = bf2f(u1), f2 = bf2f(u2), f3 = bf2f(u3);
    sx += (f0.x + f1.x) + (f2.x + f3.x);
    sy += (f0.y + f1.y) + (f2.y + f3.y);
  }
  for (; n < end; n += 4) {
    float2 f = bf2f(p[(size_t)n * 64 + t]);
    sx += f.x; sy += f.y;
  }

  __shared__ float sh[4][128];
  sh[wv][2 * t] = sx;
  sh[wv][2 * t + 1] = sy;
  __syncthreads();
  if (wv == 0) {
    float vx = sh[0][2 * t] + sh[1][2 * t] + sh[2][2 * t] + sh[3][2 * t];
    float vy = sh[0][2 * t + 1] + sh[1][2 * t + 1] + sh[2][2 * t + 1] + sh[3][2 * t + 1];
    float c = fmaxf((float)(end - start), 1.f);
    pooled_raw[g * KF + 2 * t] = vx / c;
    pooled_raw[g * KF + 2 * t + 1] = vy / c;
  }
}

// ---------------- fused mini-GEMM (pooled = praw @ W2 + b2) + heads ----------------

__global__ __launch_bounds__(256) void k_heads(const float* __restrict__ praw,
                                               const float* __restrict__ W2,
                                               const float* __restrict__ b2,
                                               const float* __restrict__ Wg,
                                               const float* __restrict__ bg,
                                               const float* __restrict__ Wf,
                                               const float* __restrict__ bfb,
                                               float* __restrict__ out) {
  int b = blockIdx.x;
  int t = threadIdx.x;  // 256
  __shared__ float pr[KF];
  __shared__ float p[H2F];
  if (t < KF) pr[t] = praw[b * KF + t];
  __syncthreads();
  float acc = b2[t];
#pragma unroll 8
  for (int d = 0; d < KF; ++d) acc = fmaf(pr[d], W2[d * H2F + t], acc);
  p[t] = acc;
  __syncthreads();
  if (t < NGRP) {
    float a = bg[t];
    for (int d = 0; d < H2F; ++d) a = fmaf(p[d], Wg[d * NGRP + t], a);
    out[b * NGRP + t] = a;
  } else if (t >= 64 && t < 64 + NGRP * NFAM) {
    int u = t - 64;
    int g = u / NFAM;
    int ff = u % NFAM;
    float a = bfb[g * NFAM + ff];
    for (int d = 0; d < H2F; ++d) a = fmaf(p[d], Wf[(g * H2F + d) * NFAM + ff], a);
    out[NGR * NGRP + (size_t)g * NGR * NFAM + b * NFAM + ff] = a;
  }
}

// ---------------- launch ----------------

extern "C" void kernel_launch(void* const* d_in, const int* in_sizes, int n_in,
                              void* d_out, int out_size, void* d_ws, size_t ws_size,
                              hipStream_t stream) {
  const float* x    = (const float*)d_in[0];
  const int*   ei   = (const int*)d_in[1];
  const int*   batch= (const int*)d_in[2];
  const float* W1   = (const float*)d_in[3];
  const float* b1   = (const float*)d_in[4];
  const float* W2   = (const float*)d_in[5];
  const float* b2   = (const float*)d_in[6];
  const float* Wg   = (const float*)d_in[7];
  const float* bg   = (const float*)d_in[8];
  const float* Wf   = (const float*)d_in[9];
  const float* bfb  = (const float*)d_in[10];
  float* out = (float*)d_out;

  char* w = (char*)d_ws;
  auto take = [&](size_t bytes) {
    char* p = w;
    w += (bytes + 255) & ~(size_t)255;
    return (void*)p;
  };
  int*   mat   = (int*)take((size_t)NT * NCHUNK * 4);
  int*   tot   = (int*)take((size_t)NCHUNK * 4);
  int*   cbase = (int*)take((size_t)(NCHUNK + 1) * 4);
  int2*  erec  = (int2*)take((size_t)NT * PT * 8);
  int*   esrc  = (int*)take((size_t)NE * 4);
  int*   rowptr= (int*)take((size_t)(NN + 1) * 4);
  float* dinv  = (float*)take((size_t)NN * 4);
  float* praw  = (float*)take((size_t)NGR * KF * 4);
  unsigned short* Bp1 = (unsigned short*)take((size_t)KF * KF * 2);
  unsigned* xw1 = (unsigned*)take((size_t)NN * KF * 2);
  unsigned* h1  = (unsigned*)take((size_t)NN * KF * 2);
  unsigned* agg2= (unsigned*)take((size_t)NN * KF * 2);

  k_phist<<<NT, 256, 0, stream>>>(ei, mat);
  k_colsum<<<(NCHUNK + 3) / 4, 256, 0, stream>>>(mat, tot);
  k_scantot<<<1, 256, 0, stream>>>(tot, cbase);
  k_colfix<<<(NCHUNK + 3) / 4, 256, 0, stream>>>(mat, cbase);
  k_pscatter<<<NT, 256, 0, stream>>>(ei, mat, erec);
  k_sort<<<NCHUNK, 256, 0, stream>>>(erec, cbase, esrc, rowptr, dinv);

  k_prepB<<<(KF * KF + 255) / 256, 256, 0, stream>>>(W1, Bp1, KF);
  k_gemm_mfma<<<1563, 256, 0, stream>>>(x, Bp1, dinv, (unsigned short*)xw1);

  k_agg<true><<<NN / 2, 128, 0, stream>>>(xw1, b1, rowptr, esrc, dinv, h1);
  k_agg<false><<<NN / 2, 128, 0, stream>>>(h1, nullptr, rowptr, esrc, dinv, agg2);

  k_pool<<<NGR, 256, 0, stream>>>(agg2, batch, praw);
  k_heads<<<NGR, 256, 0, stream>>>(praw, W2, b2, Wg, bg, Wf, bfb, out);
}

// Round 10
// 341.160 us; speedup vs baseline: 2.7134x; 1.0197x over previous
//
#include <hip/hip_runtime.h>

#define NN 100000     // nodes
#define NE 1600000    // edges
#define NGR 512       // graphs
#define KF 128        // IN_F == H1
#define H2F 256
#define NGRP 16
#define NFAM 10

#define CH 128                          // nodes per chunk
#define NCHUNK ((NN + CH - 1) / CH)     // 782
#define PT 6656                         // edges per partition tile
#define NT ((NE + PT - 1) / PT)         // 241
#define PREPB_BLKS 64                   // 128*128/256

typedef __attribute__((ext_vector_type(8))) short short8;
typedef __attribute__((ext_vector_type(4))) float floatx4;

__device__ __forceinline__ unsigned short f2bf(float f) {
  unsigned u = __float_as_uint(f);
  unsigned r = (u + 0x7fff + ((u >> 16) & 1)) >> 16;
  return (unsigned short)r;
}
__device__ __forceinline__ float2 bf2f(unsigned u) {
  float2 r;
  r.x = __uint_as_float(u << 16);
  r.y = __uint_as_float(u & 0xffff0000u);
  return r;
}

// ---------------- merged: per-tile chunk histogram -> global tot  |  W1 swizzle ----------------

__global__ __launch_bounds__(256) void k_histprep(const int* __restrict__ ei,
                                                  int* __restrict__ tot,
                                                  const float* __restrict__ W,
                                                  unsigned short* __restrict__ Bp) {
  __shared__ int lh[NCHUNK];
  int tid = threadIdx.x;
  if (blockIdx.x >= NT) {
    // prepB: Bp[((kc*8 + nc)*64 + l)*8 + j] = bf16(W[(kc*32+(l>>4)*8+j)*128 + nc*16+(l&15)])
    int idx = (blockIdx.x - NT) * 256 + tid;
    int j = idx & 7;
    int l = (idx >> 3) & 63;
    int rest = idx >> 9;
    int nc = rest & 7;
    int kc = rest >> 3;
    int k = kc * 32 + (l >> 4) * 8 + j;
    int nn = nc * 16 + (l & 15);
    Bp[idx] = f2bf(W[k * KF + nn]);
    return;
  }
  for (int g = tid; g < NCHUNK; g += 256) lh[g] = 0;
  __syncthreads();
  int base = blockIdx.x * PT;
  int nv = min(PT, NE - base);
  for (int i = tid; i < nv; i += 256) atomicAdd(&lh[ei[NE + base + i] >> 7], 1);
  __syncthreads();
  for (int g = tid; g < NCHUNK; g += 256) {
    int v = lh[g];
    if (v) atomicAdd(&tot[g], v);
  }
}

// ---------------- exclusive scan tot -> cbase; init cursor ----------------

__global__ __launch_bounds__(256) void k_scantot(const int* __restrict__ tot,
                                                 int* __restrict__ cbase,
                                                 int* __restrict__ cursor) {
  __shared__ int ssc[256];
  int tid = threadIdx.x;
  int v4[4]; int loc = 0;
#pragma unroll
  for (int j = 0; j < 4; ++j) {
    int idx = tid * 4 + j;
    v4[j] = (idx < NCHUNK) ? tot[idx] : 0;
    loc += v4[j];
  }
  ssc[tid] = loc;
  __syncthreads();
  for (int off = 1; off < 256; off <<= 1) {
    int val = (tid >= off) ? ssc[tid - off] : 0;
    __syncthreads();
    ssc[tid] += val;
    __syncthreads();
  }
  int excl = ssc[tid] - loc;
#pragma unroll
  for (int j = 0; j < 4; ++j) {
    int idx = tid * 4 + j;
    if (idx < NCHUNK) { cbase[idx] = excl; cursor[idx] = excl; }
    excl += v4[j];
  }
  if (tid == 255) cbase[NCHUNK] = excl;  // == NE
}

// ---------------- partition: LDS-staged, cursor-reserved per-chunk slices ----------------

__global__ __launch_bounds__(256) void k_pscatter(const int* __restrict__ ei,
                                                  int* __restrict__ cursor,
                                                  int2* __restrict__ erec) {
  __shared__ int2 stage[PT];
  __shared__ int lstart[NCHUNK];
  __shared__ int lrun[NCHUNK];
  __shared__ int gbase[NCHUNK];
  __shared__ int ssc[256];
  int t0 = blockIdx.x, tid = threadIdx.x;
  for (int g = tid; g < NCHUNK; g += 256) lrun[g] = 0;
  __syncthreads();
  int base = t0 * PT;
  int nv = min(PT, NE - base);
  for (int i = tid; i < nv; i += 256) atomicAdd(&lrun[ei[NE + base + i] >> 7], 1);
  __syncthreads();
  // exclusive scan of counts -> lstart (4 per thread)
  int v4[4]; int loc = 0;
#pragma unroll
  for (int j = 0; j < 4; ++j) {
    int idx = tid * 4 + j;
    v4[j] = (idx < NCHUNK) ? lrun[idx] : 0;
    loc += v4[j];
  }
  ssc[tid] = loc;
  __syncthreads();
  for (int off = 1; off < 256; off <<= 1) {
    int val = (tid >= off) ? ssc[tid - off] : 0;
    __syncthreads();
    ssc[tid] += val;
    __syncthreads();
  }
  int excl = ssc[tid] - loc;
#pragma unroll
  for (int j = 0; j < 4; ++j) {
    int idx = tid * 4 + j;
    if (idx < NCHUNK) lstart[idx] = excl;
    excl += v4[j];
  }
  __syncthreads();
  // reserve global slices per chunk; reset lrun for the scatter
  for (int g = tid; g < NCHUNK; g += 256) {
    int cnt = ((g + 1 < NCHUNK) ? lstart[g + 1] : nv) - lstart[g];
    gbase[g] = cnt ? atomicAdd(&cursor[g], cnt) : 0;
    lrun[g] = lstart[g];
  }
  __syncthreads();
  for (int i = tid; i < nv; i += 256) {
    int s = ei[base + i], d = ei[NE + base + i];
    int pos = atomicAdd(&lrun[d >> 7], 1);
    stage[pos] = make_int2(s, d);
  }
  __syncthreads();
  for (int j = tid; j < nv; j += 256) {
    int2 r = stage[j];
    int g = r.y >> 7;
    erec[gbase[g] + (j - lstart[g])] = r;
  }
}

// ---------------- per-chunk counting sort into packed per-node runs (+dinv) ----------------

__global__ __launch_bounds__(256) void k_sort(const int2* __restrict__ erec,
                                              const int* __restrict__ cbase,
                                              int* __restrict__ esrc,
                                              int* __restrict__ rowptr,
                                              float* __restrict__ dinv) {
  __shared__ int hist[CH];
  __shared__ int lrun[CH];
  __shared__ int sc[256];
  const int c = blockIdx.x, tid = threadIdx.x;
  const int e0 = cbase[c], e1 = cbase[c + 1];
  const int nv = e1 - e0;
  if (tid < CH) hist[tid] = 0;
  __syncthreads();
  for (int i = tid; i < nv; i += 256) atomicAdd(&hist[erec[e0 + i].y & (CH - 1)], 1);
  __syncthreads();
  int deg = (tid < CH) ? hist[tid] : 0;
  sc[tid] = deg;
  __syncthreads();
  for (int off = 1; off < 256; off <<= 1) {
    int val = (tid >= off) ? sc[tid - off] : 0;
    __syncthreads();
    sc[tid] += val;
    __syncthreads();
  }
  int excl = sc[tid] - deg;
  int node = c * CH + tid;
  if (tid < CH) {
    lrun[tid] = excl;
    if (node < NN) {
      rowptr[node] = e0 + excl;
      dinv[node] = rsqrtf((float)(deg + 1));  // in-degree + self loop
    } else if (node == NN) {
      rowptr[NN] = e0 + excl;  // == NE (last chunk)
    }
  }
  __syncthreads();
  for (int i = tid; i < nv; i += 256) {
    int2 r = erec[e0 + i];
    int pos = atomicAdd(&lrun[r.y & (CH - 1)], 1);
    esrc[e0 + pos] = r.x;
  }
}

// ---------------- MFMA GEMM1: xw1'[n] = dinv[n] * (x[n] @ W1), bf16 out ----------------

__global__ __launch_bounds__(256) void k_gemm_mfma(const float* __restrict__ A,
                                                   const unsigned short* __restrict__ Bp,
                                                   const float* __restrict__ dinv,
                                                   unsigned short* __restrict__ C) {
  constexpr int K = 128;
  constexpr int N = KF;
  constexpr int NCH = N / 16;
  const int wv = blockIdx.x * 4 + (threadIdx.x >> 6);
  const int row0 = wv * 16;
  if (row0 >= NN) return;  // 100000 % 16 == 0
  const int lane = threadIdx.x & 63;
  const int m = lane & 15;
  const int q = lane >> 4;

  floatx4 acc[NCH];
#pragma unroll
  for (int i = 0; i < NCH; ++i) acc[i] = (floatx4){0.f, 0.f, 0.f, 0.f};

  const int arow = row0 + m;
#pragma unroll
  for (int kc = 0; kc < 4; ++kc) {
    const float* ap = A + (size_t)arow * K + kc * 32 + q * 8;
    float4 f0 = *(const float4*)ap;
    float4 f1 = *(const float4*)(ap + 4);
    short8 af;
    af[0] = (short)f2bf(f0.x); af[1] = (short)f2bf(f0.y);
    af[2] = (short)f2bf(f0.z); af[3] = (short)f2bf(f0.w);
    af[4] = (short)f2bf(f1.x); af[5] = (short)f2bf(f1.y);
    af[6] = (short)f2bf(f1.z); af[7] = (short)f2bf(f1.w);
    const unsigned short* bp = Bp + (size_t)kc * NCH * 512;
#pragma unroll
    for (int nc = 0; nc < NCH; ++nc) {
      short8 bfr = *(const short8*)(bp + (size_t)nc * 512 + lane * 8);
      acc[nc] = __builtin_amdgcn_mfma_f32_16x16x32_bf16(af, bfr, acc[nc], 0, 0, 0);
    }
  }

  float ds[4];
#pragma unroll
  for (int r = 0; r < 4; ++r) ds[r] = dinv[row0 + q * 4 + r];
#pragma unroll
  for (int nc = 0; nc < NCH; ++nc) {
#pragma unroll
    for (int r = 0; r < 4; ++r) {
      int row = row0 + q * 4 + r;
      C[(size_t)row * N + nc * 16 + m] = f2bf(acc[nc][r] * ds[r]);
    }
  }
}

// ---------------- aggregation (R6/R9 loop shape, prescaled inputs) ----------------
// agg1: h1'[n] = dinv[n] * relu( dinv[n]*(sum_s xw'[s] + xw'[n]) + b1 )
// agg2: out[n] = dinv[n] * (sum_s h1'[s] + h1'[n])

template <bool FIRST>
__global__ __launch_bounds__(128) void k_agg(const unsigned* __restrict__ p,
                                             const float* __restrict__ bias,
                                             const int* __restrict__ rowptr,
                                             const int* __restrict__ esrc,
                                             const float* __restrict__ dinv,
                                             unsigned* __restrict__ out) {
  const int n = blockIdx.x * 2 + (threadIdx.x >> 6);
  const int t = threadIdx.x & 63;

  float2 f = bf2f(p[(size_t)n * 64 + t]);
  float ax = f.x, ay = f.y;  // self term (prescaled input)

  const int r0 = rowptr[n];
  const int r1 = rowptr[n + 1];
  int i = r0;
  for (; i + 8 <= r1; i += 8) {
    int s0 = esrc[i], s1 = esrc[i + 1], s2 = esrc[i + 2], s3 = esrc[i + 3];
    int s4 = esrc[i + 4], s5 = esrc[i + 5], s6 = esrc[i + 6], s7 = esrc[i + 7];
    unsigned u0 = p[(size_t)s0 * 64 + t];
    unsigned u1 = p[(size_t)s1 * 64 + t];
    unsigned u2 = p[(size_t)s2 * 64 + t];
    unsigned u3 = p[(size_t)s3 * 64 + t];
    unsigned u4 = p[(size_t)s4 * 64 + t];
    unsigned u5 = p[(size_t)s5 * 64 + t];
    unsigned u6 = p[(size_t)s6 * 64 + t];
    unsigned u7 = p[(size_t)s7 * 64 + t];
    f = bf2f(u0); ax += f.x; ay += f.y;
    f = bf2f(u1); ax += f.x; ay += f.y;
    f = bf2f(u2); ax += f.x; ay += f.y;
    f = bf2f(u3); ax += f.x; ay += f.y;
    f = bf2f(u4); ax += f.x; ay += f.y;
    f = bf2f(u5); ax += f.x; ay += f.y;
    f = bf2f(u6); ax += f.x; ay += f.y;
    f = bf2f(u7); ax += f.x; ay += f.y;
  }
  for (; i + 4 <= r1; i += 4) {
    int s0 = esrc[i], s1 = esrc[i + 1], s2 = esrc[i + 2], s3 = esrc[i + 3];
    unsigned u0 = p[(size_t)s0 * 64 + t];
    unsigned u1 = p[(size_t)s1 * 64 + t];
    unsigned u2 = p[(size_t)s2 * 64 + t];
    unsigned u3 = p[(size_t)s3 * 64 + t];
    f = bf2f(u0); ax += f.x; ay += f.y;
    f = bf2f(u1); ax += f.x; ay += f.y;
    f = bf2f(u2); ax += f.x; ay += f.y;
    f = bf2f(u3); ax += f.x; ay += f.y;
  }
  for (; i < r1; ++i) {
    int s = esrc[i];
    f = bf2f(p[(size_t)s * 64 + t]);
    ax += f.x; ay += f.y;
  }

  const float dn = dinv[n];
  if (FIRST) {
    float2 bb = ((const float2*)bias)[t];
    ax = fmaf(dn, ax, bb.x);
    ay = fmaf(dn, ay, bb.y);
    ax = fmaxf(ax, 0.f) * dn;  // relu then prescale for conv2
    ay = fmaxf(ay, 0.f) * dn;
  } else {
    ax *= dn;
    ay *= dn;
  }
  out[(size_t)n * 64 + t] = (unsigned)f2bf(ax) | ((unsigned)f2bf(ay) << 16);
}

// ---------------- fused mean-pool + mini-GEMM + heads (one block per graph) ----------------

__global__ __launch_bounds__(256) void k_poolheads(const unsigned* __restrict__ hp,
                                                   const int* __restrict__ batch,
                                                   const float* __restrict__ W2,
                                                   const float* __restrict__ b2,
                                                   const float* __restrict__ Wg,
                                                   const float* __restrict__ bg,
                                                   const float* __restrict__ Wf,
                                                   const float* __restrict__ bfb,
                                                   float* __restrict__ out) {
  __shared__ float sh[4][128];
  __shared__ float pr[KF];
  __shared__ float p[H2F];
  __shared__ int bnd[2];
  const int g = blockIdx.x;
  const int tid = threadIdx.x;
  if (tid < 2) {
    int target = g + tid;
    int lo = 0, hi = NN;
    while (lo < hi) { int mid = (lo + hi) >> 1; if (batch[mid] < target) lo = mid + 1; else hi = mid; }
    bnd[tid] = lo;
  }
  __syncthreads();
  const int start = bnd[0], end = bnd[1];
  const int t = tid & 63, wv = tid >> 6;

  float sx = 0.f, sy = 0.f;
  int n = start + wv;
  for (; n + 12 < end; n += 16) {
    unsigned u0 = hp[(size_t)n * 64 + t];
    unsigned u1 = hp[(size_t)(n + 4) * 64 + t];
    unsigned u2 = hp[(size_t)(n + 8) * 64 + t];
    unsigned u3 = hp[(size_t)(n + 12) * 64 + t];
    float2 f0 = bf2f(u0), f1 = bf2f(u1), f2 = bf2f(u2), f3 = bf2f(u3);
    sx += (f0.x + f1.x) + (f2.x + f3.x);
    sy += (f0.y + f1.y) + (f2.y + f3.y);
  }
  for (; n < end; n += 4) {
    float2 f = bf2f(hp[(size_t)n * 64 + t]);
    sx += f.x; sy += f.y;
  }
  sh[wv][2 * t] = sx;
  sh[wv][2 * t + 1] = sy;
  __syncthreads();
  if (wv == 0) {
    float vx = sh[0][2 * t] + sh[1][2 * t] + sh[2][2 * t] + sh[3][2 * t];
    float vy = sh[0][2 * t + 1] + sh[1][2 * t + 1] + sh[2][2 * t + 1] + sh[3][2 * t + 1];
    float c = fmaxf((float)(end - start), 1.f);
    pr[2 * t] = vx / c;
    pr[2 * t + 1] = vy / c;
  }
  __syncthreads();
  // pooled = pr @ W2 + b2  (each thread one of 256 output features)
  float acc = b2[tid];
#pragma unroll 8
  for (int d = 0; d < KF; ++d) acc = fmaf(pr[d], W2[d * H2F + tid], acc);
  p[tid] = acc;
  __syncthreads();
  if (tid < NGRP) {
    float a = bg[tid];
    for (int d = 0; d < H2F; ++d) a = fmaf(p[d], Wg[d * NGRP + tid], a);
    out[g * NGRP + tid] = a;
  } else if (tid >= 64 && tid < 64 + NGRP * NFAM) {
    int u = tid - 64;
    int gg = u / NFAM;
    int ff = u % NFAM;
    float a = bfb[gg * NFAM + ff];
    for (int d = 0; d < H2F; ++d) a = fmaf(p[d], Wf[(gg * H2F + d) * NFAM + ff], a);
    out[NGR * NGRP + (size_t)gg * NGR * NFAM + g * NFAM + ff] = a;
  }
}

// ---------------- launch ----------------

extern "C" void kernel_launch(void* const* d_in, const int* in_sizes, int n_in,
                              void* d_out, int out_size, void* d_ws, size_t ws_size,
                              hipStream_t stream) {
  const float* x    = (const float*)d_in[0];
  const int*   ei   = (const int*)d_in[1];
  const int*   batch= (const int*)d_in[2];
  const float* W1   = (const float*)d_in[3];
  const float* b1   = (const float*)d_in[4];
  const float* W2   = (const float*)d_in[5];
  const float* b2   = (const float*)d_in[6];
  const float* Wg   = (const float*)d_in[7];
  const float* bg   = (const float*)d_in[8];
  const float* Wf   = (const float*)d_in[9];
  const float* bfb  = (const float*)d_in[10];
  float* out = (float*)d_out;

  char* w = (char*)d_ws;
  auto take = [&](size_t bytes) {
    char* p = w;
    w += (bytes + 255) & ~(size_t)255;
    return (void*)p;
  };
  int*   tot   = (int*)take((size_t)NCHUNK * 4);
  int*   cbase = (int*)take((size_t)(NCHUNK + 1) * 4);
  int*   cursor= (int*)take((size_t)NCHUNK * 4);
  int2*  erec  = (int2*)take((size_t)NE * 8);
  int*   esrc  = (int*)take((size_t)NE * 4);
  int*   rowptr= (int*)take((size_t)(NN + 1) * 4);
  float* dinv  = (float*)take((size_t)NN * 4);
  unsigned short* Bp1 = (unsigned short*)take((size_t)KF * KF * 2);
  unsigned* xw1 = (unsigned*)take((size_t)NN * KF * 2);
  unsigned* h1  = (unsigned*)take((size_t)NN * KF * 2);
  unsigned* agg2= (unsigned*)take((size_t)NN * KF * 2);

  hipMemsetAsync(tot, 0, (size_t)NCHUNK * 4, stream);
  k_histprep<<<NT + PREPB_BLKS, 256, 0, stream>>>(ei, tot, W1, Bp1);
  k_scantot<<<1, 256, 0, stream>>>(tot, cbase, cursor);
  k_pscatter<<<NT, 256, 0, stream>>>(ei, cursor, erec);
  k_sort<<<NCHUNK, 256, 0, stream>>>(erec, cbase, esrc, rowptr, dinv);

  k_gemm_mfma<<<1563, 256, 0, stream>>>(x, Bp1, dinv, (unsigned short*)xw1);

  k_agg<true><<<NN / 2, 128, 0, stream>>>(xw1, b1, rowptr, esrc, dinv, h1);
  k_agg<false><<<NN / 2, 128, 0, stream>>>(h1, nullptr, rowptr, esrc, dinv, agg2);

  k_poolheads<<<NGR, 256, 0, stream>>>(agg2, batch, W2, b2, Wg, bg, Wf, bfb, out);
}

// Round 11
// 335.216 us; speedup vs baseline: 2.7615x; 1.0177x over previous
//
#include <hip/hip_runtime.h>

#define NN 100000     // nodes
#define NE 1600000    // edges
#define NGR 512       // graphs
#define KF 128        // IN_F == H1
#define H2F 256
#define NGRP 16
#define NFAM 10

#define CH 128                          // nodes per chunk
#define NCHUNK ((NN + CH - 1) / CH)     // 782
#define PT 6656                         // edges per partition tile
#define NT ((NE + PT - 1) / PT)         // 241
#define PREPB_BLKS 64                   // 128*128/256

typedef __attribute__((ext_vector_type(8))) short short8;
typedef __attribute__((ext_vector_type(4))) float floatx4;

__device__ __forceinline__ unsigned short f2bf(float f) {
  unsigned u = __float_as_uint(f);
  unsigned r = (u + 0x7fff + ((u >> 16) & 1)) >> 16;
  return (unsigned short)r;
}
__device__ __forceinline__ float2 bf2f(unsigned u) {
  float2 r;
  r.x = __uint_as_float(u << 16);
  r.y = __uint_as_float(u & 0xffff0000u);
  return r;
}

// ---------------- merged: per-tile chunk histogram -> global tot  |  W1 swizzle ----------------

__global__ __launch_bounds__(256) void k_histprep(const int* __restrict__ ei,
                                                  int* __restrict__ tot,
                                                  const float* __restrict__ W,
                                                  unsigned short* __restrict__ Bp) {
  __shared__ int lh[NCHUNK];
  int tid = threadIdx.x;
  if (blockIdx.x >= NT) {
    int idx = (blockIdx.x - NT) * 256 + tid;
    int j = idx & 7;
    int l = (idx >> 3) & 63;
    int rest = idx >> 9;
    int nc = rest & 7;
    int kc = rest >> 3;
    int k = kc * 32 + (l >> 4) * 8 + j;
    int nn = nc * 16 + (l & 15);
    Bp[idx] = f2bf(W[k * KF + nn]);
    return;
  }
  for (int g = tid; g < NCHUNK; g += 256) lh[g] = 0;
  __syncthreads();
  int base = blockIdx.x * PT;
  int nv = min(PT, NE - base);
  for (int i = tid; i < nv; i += 256) atomicAdd(&lh[ei[NE + base + i] >> 7], 1);
  __syncthreads();
  for (int g = tid; g < NCHUNK; g += 256) {
    int v = lh[g];
    if (v) atomicAdd(&tot[g], v);
  }
}

// ---------------- exclusive scan tot -> cbase; init cursor ----------------

__global__ __launch_bounds__(256) void k_scantot(const int* __restrict__ tot,
                                                 int* __restrict__ cbase,
                                                 int* __restrict__ cursor) {
  __shared__ int ssc[256];
  int tid = threadIdx.x;
  int v4[4]; int loc = 0;
#pragma unroll
  for (int j = 0; j < 4; ++j) {
    int idx = tid * 4 + j;
    v4[j] = (idx < NCHUNK) ? tot[idx] : 0;
    loc += v4[j];
  }
  ssc[tid] = loc;
  __syncthreads();
  for (int off = 1; off < 256; off <<= 1) {
    int val = (tid >= off) ? ssc[tid - off] : 0;
    __syncthreads();
    ssc[tid] += val;
    __syncthreads();
  }
  int excl = ssc[tid] - loc;
#pragma unroll
  for (int j = 0; j < 4; ++j) {
    int idx = tid * 4 + j;
    if (idx < NCHUNK) { cbase[idx] = excl; cursor[idx] = excl; }
    excl += v4[j];
  }
  if (tid == 255) cbase[NCHUNK] = excl;  // == NE
}

// ---------------- partition: LDS-staged, cursor-reserved per-chunk slices ----------------

__global__ __launch_bounds__(256) void k_pscatter(const int* __restrict__ ei,
                                                  int* __restrict__ cursor,
                                                  int2* __restrict__ erec) {
  __shared__ int2 stage[PT];
  __shared__ int lstart[NCHUNK];
  __shared__ int lrun[NCHUNK];
  __shared__ int gbase[NCHUNK];
  __shared__ int ssc[256];
  int t0 = blockIdx.x, tid = threadIdx.x;
  for (int g = tid; g < NCHUNK; g += 256) lrun[g] = 0;
  __syncthreads();
  int base = t0 * PT;
  int nv = min(PT, NE - base);
  for (int i = tid; i < nv; i += 256) atomicAdd(&lrun[ei[NE + base + i] >> 7], 1);
  __syncthreads();
  int v4[4]; int loc = 0;
#pragma unroll
  for (int j = 0; j < 4; ++j) {
    int idx = tid * 4 + j;
    v4[j] = (idx < NCHUNK) ? lrun[idx] : 0;
    loc += v4[j];
  }
  ssc[tid] = loc;
  __syncthreads();
  for (int off = 1; off < 256; off <<= 1) {
    int val = (tid >= off) ? ssc[tid - off] : 0;
    __syncthreads();
    ssc[tid] += val;
    __syncthreads();
  }
  int excl = ssc[tid] - loc;
#pragma unroll
  for (int j = 0; j < 4; ++j) {
    int idx = tid * 4 + j;
    if (idx < NCHUNK) lstart[idx] = excl;
    excl += v4[j];
  }
  __syncthreads();
  for (int g = tid; g < NCHUNK; g += 256) {
    int cnt = ((g + 1 < NCHUNK) ? lstart[g + 1] : nv) - lstart[g];
    gbase[g] = cnt ? atomicAdd(&cursor[g], cnt) : 0;
    lrun[g] = lstart[g];
  }
  __syncthreads();
  for (int i = tid; i < nv; i += 256) {
    int s = ei[base + i], d = ei[NE + base + i];
    int pos = atomicAdd(&lrun[d >> 7], 1);
    stage[pos] = make_int2(s, d);
  }
  __syncthreads();
  for (int j = tid; j < nv; j += 256) {
    int2 r = stage[j];
    int g = r.y >> 7;
    erec[gbase[g] + (j - lstart[g])] = r;
  }
}

// ---------------- per-chunk counting sort into packed per-node runs (+dinv) ----------------

__global__ __launch_bounds__(256) void k_sort(const int2* __restrict__ erec,
                                              const int* __restrict__ cbase,
                                              int* __restrict__ esrc,
                                              int* __restrict__ rowptr,
                                              float* __restrict__ dinv) {
  __shared__ int hist[CH];
  __shared__ int lrun[CH];
  __shared__ int sc[256];
  const int c = blockIdx.x, tid = threadIdx.x;
  const int e0 = cbase[c], e1 = cbase[c + 1];
  const int nv = e1 - e0;
  if (tid < CH) hist[tid] = 0;
  __syncthreads();
  for (int i = tid; i < nv; i += 256) atomicAdd(&hist[erec[e0 + i].y & (CH - 1)], 1);
  __syncthreads();
  int deg = (tid < CH) ? hist[tid] : 0;
  sc[tid] = deg;
  __syncthreads();
  for (int off = 1; off < 256; off <<= 1) {
    int val = (tid >= off) ? sc[tid - off] : 0;
    __syncthreads();
    sc[tid] += val;
    __syncthreads();
  }
  int excl = sc[tid] - deg;
  int node = c * CH + tid;
  if (tid < CH) {
    lrun[tid] = excl;
    if (node < NN) {
      rowptr[node] = e0 + excl;
      dinv[node] = rsqrtf((float)(deg + 1));  // in-degree + self loop
    } else if (node == NN) {
      rowptr[NN] = e0 + excl;  // == NE (last chunk)
    }
  }
  __syncthreads();
  for (int i = tid; i < nv; i += 256) {
    int2 r = erec[e0 + i];
    int pos = atomicAdd(&lrun[r.y & (CH - 1)], 1);
    esrc[e0 + pos] = r.x;
  }
}

// ---------------- MFMA GEMM1: xw1'[n] = dinv[n] * (x[n] @ W1), bf16 out ----------------

__global__ __launch_bounds__(256) void k_gemm_mfma(const float* __restrict__ A,
                                                   const unsigned short* __restrict__ Bp,
                                                   const float* __restrict__ dinv,
                                                   unsigned short* __restrict__ C) {
  constexpr int K = 128;
  constexpr int N = KF;
  constexpr int NCH = N / 16;
  const int wv = blockIdx.x * 4 + (threadIdx.x >> 6);
  const int row0 = wv * 16;
  if (row0 >= NN) return;  // 100000 % 16 == 0
  const int lane = threadIdx.x & 63;
  const int m = lane & 15;
  const int q = lane >> 4;

  floatx4 acc[NCH];
#pragma unroll
  for (int i = 0; i < NCH; ++i) acc[i] = (floatx4){0.f, 0.f, 0.f, 0.f};

  const int arow = row0 + m;
#pragma unroll
  for (int kc = 0; kc < 4; ++kc) {
    const float* ap = A + (size_t)arow * K + kc * 32 + q * 8;
    float4 f0 = *(const float4*)ap;
    float4 f1 = *(const float4*)(ap + 4);
    short8 af;
    af[0] = (short)f2bf(f0.x); af[1] = (short)f2bf(f0.y);
    af[2] = (short)f2bf(f0.z); af[3] = (short)f2bf(f0.w);
    af[4] = (short)f2bf(f1.x); af[5] = (short)f2bf(f1.y);
    af[6] = (short)f2bf(f1.z); af[7] = (short)f2bf(f1.w);
    const unsigned short* bp = Bp + (size_t)kc * NCH * 512;
#pragma unroll
    for (int nc = 0; nc < NCH; ++nc) {
      short8 bfr = *(const short8*)(bp + (size_t)nc * 512 + lane * 8);
      acc[nc] = __builtin_amdgcn_mfma_f32_16x16x32_bf16(af, bfr, acc[nc], 0, 0, 0);
    }
  }

  float ds[4];
#pragma unroll
  for (int r = 0; r < 4; ++r) ds[r] = dinv[row0 + q * 4 + r];
#pragma unroll
  for (int nc = 0; nc < NCH; ++nc) {
#pragma unroll
    for (int r = 0; r < 4; ++r) {
      int row = row0 + q * 4 + r;
      C[(size_t)row * N + nc * 16 + m] = f2bf(acc[nc][r] * ds[r]);
    }
  }
}

// ---------------- aggregation: 16-deep MLP tier + 8/4/1 tails ----------------
// agg1: h1'[n] = dinv[n] * relu( dinv[n]*(sum_s xw'[s] + xw'[n]) + b1 )
// agg2: out[n] = dinv[n] * (sum_s h1'[s] + h1'[n])

template <bool FIRST>
__global__ __launch_bounds__(128) void k_agg(const unsigned* __restrict__ p,
                                             const float* __restrict__ bias,
                                             const int* __restrict__ rowptr,
                                             const int* __restrict__ esrc,
                                             const float* __restrict__ dinv,
                                             unsigned* __restrict__ out) {
  const int n = blockIdx.x * 2 + (threadIdx.x >> 6);
  const int t = threadIdx.x & 63;

  float2 f = bf2f(p[(size_t)n * 64 + t]);
  float ax = f.x, ay = f.y;  // self term (prescaled input)

  const int r0 = rowptr[n];
  const int r1 = rowptr[n + 1];
  int i = r0;
  for (; i + 16 <= r1; i += 16) {
    int s[16];
#pragma unroll
    for (int j = 0; j < 16; ++j) s[j] = esrc[i + j];
    unsigned u[16];
#pragma unroll
    for (int j = 0; j < 16; ++j) u[j] = p[(size_t)s[j] * 64 + t];
#pragma unroll
    for (int j = 0; j < 16; ++j) {
      f = bf2f(u[j]); ax += f.x; ay += f.y;
    }
  }
  for (; i + 8 <= r1; i += 8) {
    int s0 = esrc[i], s1 = esrc[i + 1], s2 = esrc[i + 2], s3 = esrc[i + 3];
    int s4 = esrc[i + 4], s5 = esrc[i + 5], s6 = esrc[i + 6], s7 = esrc[i + 7];
    unsigned u0 = p[(size_t)s0 * 64 + t];
    unsigned u1 = p[(size_t)s1 * 64 + t];
    unsigned u2 = p[(size_t)s2 * 64 + t];
    unsigned u3 = p[(size_t)s3 * 64 + t];
    unsigned u4 = p[(size_t)s4 * 64 + t];
    unsigned u5 = p[(size_t)s5 * 64 + t];
    unsigned u6 = p[(size_t)s6 * 64 + t];
    unsigned u7 = p[(size_t)s7 * 64 + t];
    f = bf2f(u0); ax += f.x; ay += f.y;
    f = bf2f(u1); ax += f.x; ay += f.y;
    f = bf2f(u2); ax += f.x; ay += f.y;
    f = bf2f(u3); ax += f.x; ay += f.y;
    f = bf2f(u4); ax += f.x; ay += f.y;
    f = bf2f(u5); ax += f.x; ay += f.y;
    f = bf2f(u6); ax += f.x; ay += f.y;
    f = bf2f(u7); ax += f.x; ay += f.y;
  }
  for (; i + 4 <= r1; i += 4) {
    int s0 = esrc[i], s1 = esrc[i + 1], s2 = esrc[i + 2], s3 = esrc[i + 3];
    unsigned u0 = p[(size_t)s0 * 64 + t];
    unsigned u1 = p[(size_t)s1 * 64 + t];
    unsigned u2 = p[(size_t)s2 * 64 + t];
    unsigned u3 = p[(size_t)s3 * 64 + t];
    f = bf2f(u0); ax += f.x; ay += f.y;
    f = bf2f(u1); ax += f.x; ay += f.y;
    f = bf2f(u2); ax += f.x; ay += f.y;
    f = bf2f(u3); ax += f.x; ay += f.y;
  }
  for (; i < r1; ++i) {
    int s = esrc[i];
    f = bf2f(p[(size_t)s * 64 + t]);
    ax += f.x; ay += f.y;
  }

  const float dn = dinv[n];
  if (FIRST) {
    float2 bb = ((const float2*)bias)[t];
    ax = fmaf(dn, ax, bb.x);
    ay = fmaf(dn, ay, bb.y);
    ax = fmaxf(ax, 0.f) * dn;  // relu then prescale for conv2
    ay = fmaxf(ay, 0.f) * dn;
  } else {
    ax *= dn;
    ay *= dn;
  }
  out[(size_t)n * 64 + t] = (unsigned)f2bf(ax) | ((unsigned)f2bf(ay) << 16);
}

// ---------------- fused mean-pool + mini-GEMM + heads (one block per graph) ----------------

__global__ __launch_bounds__(256) void k_poolheads(const unsigned* __restrict__ hp,
                                                   const int* __restrict__ batch,
                                                   const float* __restrict__ W2,
                                                   const float* __restrict__ b2,
                                                   const float* __restrict__ Wg,
                                                   const float* __restrict__ bg,
                                                   const float* __restrict__ Wf,
                                                   const float* __restrict__ bfb,
                                                   float* __restrict__ out) {
  __shared__ float sh[4][128];
  __shared__ float pr[KF];
  __shared__ float p[H2F];
  __shared__ int bnd[2];
  const int g = blockIdx.x;
  const int tid = threadIdx.x;
  if (tid < 2) {
    int target = g + tid;
    int lo = 0, hi = NN;
    while (lo < hi) { int mid = (lo + hi) >> 1; if (batch[mid] < target) lo = mid + 1; else hi = mid; }
    bnd[tid] = lo;
  }
  __syncthreads();
  const int start = bnd[0], end = bnd[1];
  const int t = tid & 63, wv = tid >> 6;

  float sx = 0.f, sy = 0.f;
  int n = start + wv;
  for (; n + 12 < end; n += 16) {
    unsigned u0 = hp[(size_t)n * 64 + t];
    unsigned u1 = hp[(size_t)(n + 4) * 64 + t];
    unsigned u2 = hp[(size_t)(n + 8) * 64 + t];
    unsigned u3 = hp[(size_t)(n + 12) * 64 + t];
    float2 f0 = bf2f(u0), f1 = bf2f(u1), f2 = bf2f(u2), f3 = bf2f(u3);
    sx += (f0.x + f1.x) + (f2.x + f3.x);
    sy += (f0.y + f1.y) + (f2.y + f3.y);
  }
  for (; n < end; n += 4) {
    float2 f = bf2f(hp[(size_t)n * 64 + t]);
    sx += f.x; sy += f.y;
  }
  sh[wv][2 * t] = sx;
  sh[wv][2 * t + 1] = sy;
  __syncthreads();
  if (wv == 0) {
    float vx = sh[0][2 * t] + sh[1][2 * t] + sh[2][2 * t] + sh[3][2 * t];
    float vy = sh[0][2 * t + 1] + sh[1][2 * t + 1] + sh[2][2 * t + 1] + sh[3][2 * t + 1];
    float c = fmaxf((float)(end - start), 1.f);
    pr[2 * t] = vx / c;
    pr[2 * t + 1] = vy / c;
  }
  __syncthreads();
  float acc = b2[tid];
#pragma unroll 8
  for (int d = 0; d < KF; ++d) acc = fmaf(pr[d], W2[d * H2F + tid], acc);
  p[tid] = acc;
  __syncthreads();
  if (tid < NGRP) {
    float a = bg[tid];
    for (int d = 0; d < H2F; ++d) a = fmaf(p[d], Wg[d * NGRP + tid], a);
    out[g * NGRP + tid] = a;
  } else if (tid >= 64 && tid < 64 + NGRP * NFAM) {
    int u = tid - 64;
    int gg = u / NFAM;
    int ff = u % NFAM;
    float a = bfb[gg * NFAM + ff];
    for (int d = 0; d < H2F; ++d) a = fmaf(p[d], Wf[(gg * H2F + d) * NFAM + ff], a);
    out[NGR * NGRP + (size_t)gg * NGR * NFAM + g * NFAM + ff] = a;
  }
}

// ---------------- launch ----------------

extern "C" void kernel_launch(void* const* d_in, const int* in_sizes, int n_in,
                              void* d_out, int out_size, void* d_ws, size_t ws_size,
                              hipStream_t stream) {
  const float* x    = (const float*)d_in[0];
  const int*   ei   = (const int*)d_in[1];
  const int*   batch= (const int*)d_in[2];
  const float* W1   = (const float*)d_in[3];
  const float* b1   = (const float*)d_in[4];
  const float* W2   = (const float*)d_in[5];
  const float* b2   = (const float*)d_in[6];
  const float* Wg   = (const float*)d_in[7];
  const float* bg   = (const float*)d_in[8];
  const float* Wf   = (const float*)d_in[9];
  const float* bfb  = (const float*)d_in[10];
  float* out = (float*)d_out;

  char* w = (char*)d_ws;
  auto take = [&](size_t bytes) {
    char* p = w;
    w += (bytes + 255) & ~(size_t)255;
    return (void*)p;
  };
  int*   tot   = (int*)take((size_t)NCHUNK * 4);
  int*   cbase = (int*)take((size_t)(NCHUNK + 1) * 4);
  int*   cursor= (int*)take((size_t)NCHUNK * 4);
  int2*  erec  = (int2*)take((size_t)NE * 8);
  int*   esrc  = (int*)take((size_t)NE * 4);
  int*   rowptr= (int*)take((size_t)(NN + 1) * 4);
  float* dinv  = (float*)take((size_t)NN * 4);
  unsigned short* Bp1 = (unsigned short*)take((size_t)KF * KF * 2);
  unsigned* xw1 = (unsigned*)take((size_t)NN * KF * 2);
  unsigned* h1  = (unsigned*)take((size_t)NN * KF * 2);
  unsigned* agg2= (unsigned*)take((size_t)NN * KF * 2);

  hipMemsetAsync(tot, 0, (size_t)NCHUNK * 4, stream);
  k_histprep<<<NT + PREPB_BLKS, 256, 0, stream>>>(ei, tot, W1, Bp1);
  k_scantot<<<1, 256, 0, stream>>>(tot, cbase, cursor);
  k_pscatter<<<NT, 256, 0, stream>>>(ei, cursor, erec);
  k_sort<<<NCHUNK, 256, 0, stream>>>(erec, cbase, esrc, rowptr, dinv);

  k_gemm_mfma<<<1563, 256, 0, stream>>>(x, Bp1, dinv, (unsigned short*)xw1);

  k_agg<true><<<NN / 2, 128, 0, stream>>>(xw1, b1, rowptr, esrc, dinv, h1);
  k_agg<false><<<NN / 2, 128, 0, stream>>>(h1, nullptr, rowptr, esrc, dinv, agg2);

  k_poolheads<<<NGR, 256, 0, stream>>>(agg2, batch, W2, b2, Wg, bg, Wf, bfb, out);
}

// Round 12
// 309.618 us; speedup vs baseline: 2.9898x; 1.0827x over previous
//
#include <hip/hip_runtime.h>

#define NN 100000     // nodes
#define NE 1600000    // edges
#define NGR 512       // graphs
#define KF 128        // IN_F == H1
#define H2F 256
#define NGRP 16
#define NFAM 10

#define CH 128                          // nodes per chunk
#define NCHUNK ((NN + CH - 1) / CH)     // 782
#define PT 6656                         // edges per partition tile
#define NT ((NE + PT - 1) / PT)         // 241
#define PREPB_BLKS 64                   // 128*128/256

typedef __attribute__((ext_vector_type(8))) short short8;
typedef __attribute__((ext_vector_type(4))) float floatx4;
typedef __attribute__((ext_vector_type(2))) float floatx2;

__device__ __forceinline__ unsigned short f2bf(float f) {
  unsigned u = __float_as_uint(f);
  unsigned r = (u + 0x7fff + ((u >> 16) & 1)) >> 16;
  return (unsigned short)r;
}
__device__ __forceinline__ float2 bf2f(unsigned u) {
  float2 r;
  r.x = __uint_as_float(u << 16);
  r.y = __uint_as_float(u & 0xffff0000u);
  return r;
}
// fp8 e4m3 pair (features t, t+64) <-> floats via gfx950 HW converters
__device__ __forceinline__ unsigned short pk_fp8(float a, float b) {
  return (unsigned short)__builtin_amdgcn_cvt_pk_fp8_f32(a, b, 0, false);
}
__device__ __forceinline__ floatx2 unpk_fp8(unsigned short u) {
  return __builtin_amdgcn_cvt_pk_f32_fp8((int)u, false);
}

// ---------------- merged: per-tile chunk histogram -> global tot  |  W1 swizzle ----------------

__global__ __launch_bounds__(256) void k_histprep(const int* __restrict__ ei,
                                                  int* __restrict__ tot,
                                                  const float* __restrict__ W,
                                                  unsigned short* __restrict__ Bp) {
  __shared__ int lh[NCHUNK];
  int tid = threadIdx.x;
  if (blockIdx.x >= NT) {
    int idx = (blockIdx.x - NT) * 256 + tid;
    int j = idx & 7;
    int l = (idx >> 3) & 63;
    int rest = idx >> 9;
    int nc = rest & 7;
    int kc = rest >> 3;
    int k = kc * 32 + (l >> 4) * 8 + j;
    int nn = nc * 16 + (l & 15);
    Bp[idx] = f2bf(W[k * KF + nn]);
    return;
  }
  for (int g = tid; g < NCHUNK; g += 256) lh[g] = 0;
  __syncthreads();
  int base = blockIdx.x * PT;
  int nv = min(PT, NE - base);
  for (int i = tid; i < nv; i += 256) atomicAdd(&lh[ei[NE + base + i] >> 7], 1);
  __syncthreads();
  for (int g = tid; g < NCHUNK; g += 256) {
    int v = lh[g];
    if (v) atomicAdd(&tot[g], v);
  }
}

// ---------------- exclusive scan tot -> cbase; init cursor ----------------

__global__ __launch_bounds__(256) void k_scantot(const int* __restrict__ tot,
                                                 int* __restrict__ cbase,
                                                 int* __restrict__ cursor) {
  __shared__ int ssc[256];
  int tid = threadIdx.x;
  int v4[4]; int loc = 0;
#pragma unroll
  for (int j = 0; j < 4; ++j) {
    int idx = tid * 4 + j;
    v4[j] = (idx < NCHUNK) ? tot[idx] : 0;
    loc += v4[j];
  }
  ssc[tid] = loc;
  __syncthreads();
  for (int off = 1; off < 256; off <<= 1) {
    int val = (tid >= off) ? ssc[tid - off] : 0;
    __syncthreads();
    ssc[tid] += val;
    __syncthreads();
  }
  int excl = ssc[tid] - loc;
#pragma unroll
  for (int j = 0; j < 4; ++j) {
    int idx = tid * 4 + j;
    if (idx < NCHUNK) { cbase[idx] = excl; cursor[idx] = excl; }
    excl += v4[j];
  }
  if (tid == 255) cbase[NCHUNK] = excl;  // == NE
}

// ---------------- partition: LDS-staged, cursor-reserved per-chunk slices ----------------

__global__ __launch_bounds__(256) void k_pscatter(const int* __restrict__ ei,
                                                  int* __restrict__ cursor,
                                                  int2* __restrict__ erec) {
  __shared__ int2 stage[PT];
  __shared__ int lstart[NCHUNK];
  __shared__ int lrun[NCHUNK];
  __shared__ int gbase[NCHUNK];
  __shared__ int ssc[256];
  int t0 = blockIdx.x, tid = threadIdx.x;
  for (int g = tid; g < NCHUNK; g += 256) lrun[g] = 0;
  __syncthreads();
  int base = t0 * PT;
  int nv = min(PT, NE - base);
  for (int i = tid; i < nv; i += 256) atomicAdd(&lrun[ei[NE + base + i] >> 7], 1);
  __syncthreads();
  int v4[4]; int loc = 0;
#pragma unroll
  for (int j = 0; j < 4; ++j) {
    int idx = tid * 4 + j;
    v4[j] = (idx < NCHUNK) ? lrun[idx] : 0;
    loc += v4[j];
  }
  ssc[tid] = loc;
  __syncthreads();
  for (int off = 1; off < 256; off <<= 1) {
    int val = (tid >= off) ? ssc[tid - off] : 0;
    __syncthreads();
    ssc[tid] += val;
    __syncthreads();
  }
  int excl = ssc[tid] - loc;
#pragma unroll
  for (int j = 0; j < 4; ++j) {
    int idx = tid * 4 + j;
    if (idx < NCHUNK) lstart[idx] = excl;
    excl += v4[j];
  }
  __syncthreads();
  for (int g = tid; g < NCHUNK; g += 256) {
    int cnt = ((g + 1 < NCHUNK) ? lstart[g + 1] : nv) - lstart[g];
    gbase[g] = cnt ? atomicAdd(&cursor[g], cnt) : 0;
    lrun[g] = lstart[g];
  }
  __syncthreads();
  for (int i = tid; i < nv; i += 256) {
    int s = ei[base + i], d = ei[NE + base + i];
    int pos = atomicAdd(&lrun[d >> 7], 1);
    stage[pos] = make_int2(s, d);
  }
  __syncthreads();
  for (int j = tid; j < nv; j += 256) {
    int2 r = stage[j];
    int g = r.y >> 7;
    erec[gbase[g] + (j - lstart[g])] = r;
  }
}

// ---------------- per-chunk counting sort into packed per-node runs (+dinv) ----------------

__global__ __launch_bounds__(256) void k_sort(const int2* __restrict__ erec,
                                              const int* __restrict__ cbase,
                                              int* __restrict__ esrc,
                                              int* __restrict__ rowptr,
                                              float* __restrict__ dinv) {
  __shared__ int hist[CH];
  __shared__ int lrun[CH];
  __shared__ int sc[256];
  const int c = blockIdx.x, tid = threadIdx.x;
  const int e0 = cbase[c], e1 = cbase[c + 1];
  const int nv = e1 - e0;
  if (tid < CH) hist[tid] = 0;
  __syncthreads();
  for (int i = tid; i < nv; i += 256) atomicAdd(&hist[erec[e0 + i].y & (CH - 1)], 1);
  __syncthreads();
  int deg = (tid < CH) ? hist[tid] : 0;
  sc[tid] = deg;
  __syncthreads();
  for (int off = 1; off < 256; off <<= 1) {
    int val = (tid >= off) ? sc[tid - off] : 0;
    __syncthreads();
    sc[tid] += val;
    __syncthreads();
  }
  int excl = sc[tid] - deg;
  int node = c * CH + tid;
  if (tid < CH) {
    lrun[tid] = excl;
    if (node < NN) {
      rowptr[node] = e0 + excl;
      dinv[node] = rsqrtf((float)(deg + 1));  // in-degree + self loop
    } else if (node == NN) {
      rowptr[NN] = e0 + excl;  // == NE (last chunk)
    }
  }
  __syncthreads();
  for (int i = tid; i < nv; i += 256) {
    int2 r = erec[e0 + i];
    int pos = atomicAdd(&lrun[r.y & (CH - 1)], 1);
    esrc[e0 + pos] = r.x;
  }
}

// ---------------- MFMA GEMM1: xw1'[n] = dinv[n]*(x[n] @ W1), fp8 out ----------------
// fp8 row layout: ushort at pos t holds features (t, t+64); in C-layout these are
// cols nc*16+m and (nc+4)*16+m -- SAME lane, so packing is lane-local.

__global__ __launch_bounds__(256) void k_gemm_mfma(const float* __restrict__ A,
                                                   const unsigned short* __restrict__ Bp,
                                                   const float* __restrict__ dinv,
                                                   unsigned short* __restrict__ C) {
  constexpr int K = 128;
  constexpr int NCH = KF / 16;
  const int wv = blockIdx.x * 4 + (threadIdx.x >> 6);
  const int row0 = wv * 16;
  if (row0 >= NN) return;  // 100000 % 16 == 0
  const int lane = threadIdx.x & 63;
  const int m = lane & 15;
  const int q = lane >> 4;

  floatx4 acc[NCH];
#pragma unroll
  for (int i = 0; i < NCH; ++i) acc[i] = (floatx4){0.f, 0.f, 0.f, 0.f};

  const int arow = row0 + m;
#pragma unroll
  for (int kc = 0; kc < 4; ++kc) {
    const float* ap = A + (size_t)arow * K + kc * 32 + q * 8;
    float4 f0 = *(const float4*)ap;
    float4 f1 = *(const float4*)(ap + 4);
    short8 af;
    af[0] = (short)f2bf(f0.x); af[1] = (short)f2bf(f0.y);
    af[2] = (short)f2bf(f0.z); af[3] = (short)f2bf(f0.w);
    af[4] = (short)f2bf(f1.x); af[5] = (short)f2bf(f1.y);
    af[6] = (short)f2bf(f1.z); af[7] = (short)f2bf(f1.w);
    const unsigned short* bp = Bp + (size_t)kc * NCH * 512;
#pragma unroll
    for (int nc = 0; nc < NCH; ++nc) {
      short8 bfr = *(const short8*)(bp + (size_t)nc * 512 + lane * 8);
      acc[nc] = __builtin_amdgcn_mfma_f32_16x16x32_bf16(af, bfr, acc[nc], 0, 0, 0);
    }
  }

  float ds[4];
#pragma unroll
  for (int r = 0; r < 4; ++r) ds[r] = dinv[row0 + q * 4 + r];
#pragma unroll
  for (int nc = 0; nc < 4; ++nc) {
#pragma unroll
    for (int r = 0; r < 4; ++r) {
      int row = row0 + q * 4 + r;
      C[(size_t)row * 64 + nc * 16 + m] =
          pk_fp8(acc[nc][r] * ds[r], acc[nc + 4][r] * ds[r]);
    }
  }
}

// ---------------- aggregation: fp8 gathers, 16-deep tier + 8/4/1 tails ----------------
// lane t owns features (t, t+64).
// agg1: h1'[n] = dinv[n]*relu( dinv[n]*(sum + self) + b1 ), fp8 out
// agg2: out[n] = dinv[n]*(sum + self), bf16 out (uint: low=feat t, high=feat t+64)

template <bool FIRST>
__global__ __launch_bounds__(128) void k_agg(const unsigned short* __restrict__ p,
                                             const float* __restrict__ bias,
                                             const int* __restrict__ rowptr,
                                             const int* __restrict__ esrc,
                                             const float* __restrict__ dinv,
                                             void* __restrict__ outp) {
  const int n = blockIdx.x * 2 + (threadIdx.x >> 6);
  const int t = threadIdx.x & 63;

  floatx2 f = unpk_fp8(p[(size_t)n * 64 + t]);
  float ax = f.x, ay = f.y;  // self term (prescaled input)

  const int r0 = rowptr[n];
  const int r1 = rowptr[n + 1];
  int i = r0;
  for (; i + 16 <= r1; i += 16) {
    int s[16];
#pragma unroll
    for (int j = 0; j < 16; ++j) s[j] = esrc[i + j];
    unsigned short u[16];
#pragma unroll
    for (int j = 0; j < 16; ++j) u[j] = p[(size_t)s[j] * 64 + t];
#pragma unroll
    for (int j = 0; j < 16; ++j) {
      f = unpk_fp8(u[j]); ax += f.x; ay += f.y;
    }
  }
  for (; i + 8 <= r1; i += 8) {
    int s0 = esrc[i], s1 = esrc[i + 1], s2 = esrc[i + 2], s3 = esrc[i + 3];
    int s4 = esrc[i + 4], s5 = esrc[i + 5], s6 = esrc[i + 6], s7 = esrc[i + 7];
    unsigned short u0 = p[(size_t)s0 * 64 + t];
    unsigned short u1 = p[(size_t)s1 * 64 + t];
    unsigned short u2 = p[(size_t)s2 * 64 + t];
    unsigned short u3 = p[(size_t)s3 * 64 + t];
    unsigned short u4 = p[(size_t)s4 * 64 + t];
    unsigned short u5 = p[(size_t)s5 * 64 + t];
    unsigned short u6 = p[(size_t)s6 * 64 + t];
    unsigned short u7 = p[(size_t)s7 * 64 + t];
    f = unpk_fp8(u0); ax += f.x; ay += f.y;
    f = unpk_fp8(u1); ax += f.x; ay += f.y;
    f = unpk_fp8(u2); ax += f.x; ay += f.y;
    f = unpk_fp8(u3); ax += f.x; ay += f.y;
    f = unpk_fp8(u4); ax += f.x; ay += f.y;
    f = unpk_fp8(u5); ax += f.x; ay += f.y;
    f = unpk_fp8(u6); ax += f.x; ay += f.y;
    f = unpk_fp8(u7); ax += f.x; ay += f.y;
  }
  for (; i + 4 <= r1; i += 4) {
    int s0 = esrc[i], s1 = esrc[i + 1], s2 = esrc[i + 2], s3 = esrc[i + 3];
    unsigned short u0 = p[(size_t)s0 * 64 + t];
    unsigned short u1 = p[(size_t)s1 * 64 + t];
    unsigned short u2 = p[(size_t)s2 * 64 + t];
    unsigned short u3 = p[(size_t)s3 * 64 + t];
    f = unpk_fp8(u0); ax += f.x; ay += f.y;
    f = unpk_fp8(u1); ax += f.x; ay += f.y;
    f = unpk_fp8(u2); ax += f.x; ay += f.y;
    f = unpk_fp8(u3); ax += f.x; ay += f.y;
  }
  for (; i < r1; ++i) {
    int s = esrc[i];
    f = unpk_fp8(p[(size_t)s * 64 + t]);
    ax += f.x; ay += f.y;
  }

  const float dn = dinv[n];
  if (FIRST) {
    ax = fmaf(dn, ax, bias[t]);
    ay = fmaf(dn, ay, bias[t + 64]);
    ax = fmaxf(ax, 0.f) * dn;  // relu then prescale for conv2
    ay = fmaxf(ay, 0.f) * dn;
    ((unsigned short*)outp)[(size_t)n * 64 + t] = pk_fp8(ax, ay);
  } else {
    ax *= dn;
    ay *= dn;
    ((unsigned*)outp)[(size_t)n * 64 + t] =
        (unsigned)f2bf(ax) | ((unsigned)f2bf(ay) << 16);
  }
}

// ---------------- fused mean-pool + mini-GEMM + heads (one block per graph) ----------------
// agg2 bf16 rows: uint at pos t = features (t, t+64)

__global__ __launch_bounds__(256) void k_poolheads(const unsigned* __restrict__ hp,
                                                   const int* __restrict__ batch,
                                                   const float* __restrict__ W2,
                                                   const float* __restrict__ b2,
                                                   const float* __restrict__ Wg,
                                                   const float* __restrict__ bg,
                                                   const float* __restrict__ Wf,
                                                   const float* __restrict__ bfb,
                                                   float* __restrict__ out) {
  __shared__ float sh[4][128];
  __shared__ float pr[KF];
  __shared__ float p[H2F];
  __shared__ int bnd[2];
  const int g = blockIdx.x;
  const int tid = threadIdx.x;
  if (tid < 2) {
    int target = g + tid;
    int lo = 0, hi = NN;
    while (lo < hi) { int mid = (lo + hi) >> 1; if (batch[mid] < target) lo = mid + 1; else hi = mid; }
    bnd[tid] = lo;
  }
  __syncthreads();
  const int start = bnd[0], end = bnd[1];
  const int t = tid & 63, wv = tid >> 6;

  float sx = 0.f, sy = 0.f;
  int n = start + wv;
  for (; n + 12 < end; n += 16) {
    unsigned u0 = hp[(size_t)n * 64 + t];
    unsigned u1 = hp[(size_t)(n + 4) * 64 + t];
    unsigned u2 = hp[(size_t)(n + 8) * 64 + t];
    unsigned u3 = hp[(size_t)(n + 12) * 64 + t];
    float2 f0 = bf2f(u0), f1 = bf2f(u1), f2 = bf2f(u2), f3 = bf2f(u3);
    sx += (f0.x + f1.x) + (f2.x + f3.x);
    sy += (f0.y + f1.y) + (f2.y + f3.y);
  }
  for (; n < end; n += 4) {
    float2 f = bf2f(hp[(size_t)n * 64 + t]);
    sx += f.x; sy += f.y;
  }
  sh[wv][2 * t] = sx;
  sh[wv][2 * t + 1] = sy;
  __syncthreads();
  if (wv == 0) {
    float vx = sh[0][2 * t] + sh[1][2 * t] + sh[2][2 * t] + sh[3][2 * t];
    float vy = sh[0][2 * t + 1] + sh[1][2 * t + 1] + sh[2][2 * t + 1] + sh[3][2 * t + 1];
    float c = fmaxf((float)(end - start), 1.f);
    pr[t] = vx / c;        // feature t
    pr[t + 64] = vy / c;   // feature t+64
  }
  __syncthreads();
  float acc = b2[tid];
#pragma unroll 8
  for (int d = 0; d < KF; ++d) acc = fmaf(pr[d], W2[d * H2F + tid], acc);
  p[tid] = acc;
  __syncthreads();
  if (tid < NGRP) {
    float a = bg[tid];
    for (int d = 0; d < H2F; ++d) a = fmaf(p[d], Wg[d * NGRP + tid], a);
    out[g * NGRP + tid] = a;
  } else if (tid >= 64 && tid < 64 + NGRP * NFAM) {
    int u = tid - 64;
    int gg = u / NFAM;
    int ff = u % NFAM;
    float a = bfb[gg * NFAM + ff];
    for (int d = 0; d < H2F; ++d) a = fmaf(p[d], Wf[(gg * H2F + d) * NFAM + ff], a);
    out[NGR * NGRP + (size_t)gg * NGR * NFAM + g * NFAM + ff] = a;
  }
}

// ---------------- launch ----------------

extern "C" void kernel_launch(void* const* d_in, const int* in_sizes, int n_in,
                              void* d_out, int out_size, void* d_ws, size_t ws_size,
                              hipStream_t stream) {
  const float* x    = (const float*)d_in[0];
  const int*   ei   = (const int*)d_in[1];
  const int*   batch= (const int*)d_in[2];
  const float* W1   = (const float*)d_in[3];
  const float* b1   = (const float*)d_in[4];
  const float* W2   = (const float*)d_in[5];
  const float* b2   = (const float*)d_in[6];
  const float* Wg   = (const float*)d_in[7];
  const float* bg   = (const float*)d_in[8];
  const float* Wf   = (const float*)d_in[9];
  const float* bfb  = (const float*)d_in[10];
  float* out = (float*)d_out;

  char* w = (char*)d_ws;
  auto take = [&](size_t bytes) {
    char* p = w;
    w += (bytes + 255) & ~(size_t)255;
    return (void*)p;
  };
  int*   tot   = (int*)take((size_t)NCHUNK * 4);
  int*   cbase = (int*)take((size_t)(NCHUNK + 1) * 4);
  int*   cursor= (int*)take((size_t)NCHUNK * 4);
  int2*  erec  = (int2*)take((size_t)NE * 8);
  int*   esrc  = (int*)take((size_t)NE * 4);
  int*   rowptr= (int*)take((size_t)(NN + 1) * 4);
  float* dinv  = (float*)take((size_t)NN * 4);
  unsigned short* Bp1 = (unsigned short*)take((size_t)KF * KF * 2);
  unsigned short* xw1 = (unsigned short*)take((size_t)NN * 64 * 2);  // fp8 pairs
  unsigned short* h1  = (unsigned short*)take((size_t)NN * 64 * 2);  // fp8 pairs
  unsigned* agg2= (unsigned*)take((size_t)NN * KF * 2);

  hipMemsetAsync(tot, 0, (size_t)NCHUNK * 4, stream);
  k_histprep<<<NT + PREPB_BLKS, 256, 0, stream>>>(ei, tot, W1, Bp1);
  k_scantot<<<1, 256, 0, stream>>>(tot, cbase, cursor);
  k_pscatter<<<NT, 256, 0, stream>>>(ei, cursor, erec);
  k_sort<<<NCHUNK, 256, 0, stream>>>(erec, cbase, esrc, rowptr, dinv);

  k_gemm_mfma<<<1563, 256, 0, stream>>>(x, Bp1, dinv, xw1);

  k_agg<true><<<NN / 2, 128, 0, stream>>>(xw1, b1, rowptr, esrc, dinv, h1);
  k_agg<false><<<NN / 2, 128, 0, stream>>>(h1, nullptr, rowptr, esrc, dinv, agg2);

  k_poolheads<<<NGR, 256, 0, stream>>>(agg2, batch, W2, b2, Wg, bg, Wf, bfb, out);
}